// Round 12
// baseline (238.152 us; speedup 1.0000x reference)
//
#include <hip/hip_runtime.h>
#include <hip/hip_fp16.h>

// GCN forward: 3x (MFMA GEMM + normalized adjacency aggregate + ReLU) + mean-pool + linear + log_softmax
// N=50000, E=800000, F=H=128, C=10, G=512
// Round 12: gather is miss-queue x latency bound (r10 ILP-null, r11 occupancy-null).
// Fix latency: quarter-major H layout HQ[q][n+1][32]; phase-1 loops q outermost so
// the hot gather slice is 3.2 MB -> per-XCD L2-resident (blocks phase-aligned by
// equal work). Padding 8->4 (cuts ~12% dummy edges vs pad8's ~24%).

#define FEAT 128
#define NCLASS 10
#define NB_MAX 512  // max dst buckets (n <= 65536 here: 391)

typedef _Float16 h8 __attribute__((ext_vector_type(8)));
typedef float f4 __attribute__((ext_vector_type(4)));

// LDS tile swizzle: row stride 256B; XOR row&7 into byte bits 4..6.
__device__ inline int swz(int row, int cbyte) { return row * 256 + (cbyte ^ ((row & 7) << 4)); }

__device__ inline float2 uh2f2(unsigned u) {
  __half2 h = *reinterpret_cast<__half2*>(&u);
  return make_float2(__low2float(h), __high2float(h));
}

// ---- pass 0 combined: hist (blocks<hb) + Wt convert + bounds + sentinel ----
__global__ void __launch_bounds__(256) prep_kernel(const int* __restrict__ ei,
                                                   int* __restrict__ bhist,
                                                   int ne, int nb, int epb, int hb,
                                                   const float* __restrict__ W0,
                                                   const float* __restrict__ W1,
                                                   const float* __restrict__ W2,
                                                   _Float16* __restrict__ Wt, int wtb,
                                                   const int* __restrict__ batch,
                                                   int* __restrict__ gstart, int n, int g,
                                                   unsigned* __restrict__ HQA32,
                                                   unsigned* __restrict__ HQB32, int nblk) {
  int t = threadIdx.x;
  if (blockIdx.x == nblk - 1) {
    // zero the 4 sentinel quarter-rows (node n) of both H buffers
    if (t < 128) {
      unsigned* H = (t >> 6) ? HQB32 : HQA32;
      int q = (t >> 4) & 3;
      H[(size_t)q * (n + 1) * 16 + (size_t)n * 16 + (t & 15)] = 0u;
    }
    return;
  }
  if (blockIdx.x >= hb + wtb) {
    // graph boundaries from sorted batch
    int i = (blockIdx.x - hb - wtb) * 256 + t;
    if (i >= n) return;
    int bi = batch[i];
    int bp = (i == 0) ? -1 : batch[i - 1];
    for (int q = bp + 1; q <= bi; ++q) gstart[q] = i;
    if (i == n - 1)
      for (int q = bi + 1; q <= g; ++q) gstart[q] = n;
    return;
  }
  if (blockIdx.x >= hb) {
    // Wt[l][n][k] = W_l[k][n]
    int i = (blockIdx.x - hb) * 256 + t;
    if (i < 3 * FEAT * FEAT) {
      int l = i / (FEAT * FEAT);
      int r = i - l * (FEAT * FEAT);
      int nn = r >> 7, kk = r & 127;
      const float* W = (l == 0) ? W0 : (l == 1) ? W1 : W2;
      Wt[i] = (_Float16)W[kk * FEAT + nn];
    }
    return;
  }
  __shared__ int lh[NB_MAX];
  for (int i = t; i < nb; i += 256) lh[i] = 0;
  __syncthreads();
  int r0 = blockIdx.x * epb;
  int r1 = min(r0 + epb, ne);
  for (int k = r0 + t; k < r1; k += 256) atomicAdd(&lh[ei[ne + k] >> 7], 1);
  __syncthreads();
  for (int i = t; i < nb; i += 256)
    if (lh[i]) atomicAdd(&bhist[i], lh[i]);
}

// ---- exclusive scan of bucket counts -> bstart (kept) and bcur (consumed) ----
__global__ void __launch_bounds__(512) bscan_kernel(const int* __restrict__ bhist,
                                                    int* __restrict__ bstart,
                                                    int* __restrict__ bcur,
                                                    int nb, int ne) {
  __shared__ int sh[512];
  int t = threadIdx.x;
  int v = (t < nb) ? bhist[t] : 0;
  sh[t] = v;
  __syncthreads();
  int x = v;
  for (int d = 1; d < 512; d <<= 1) {
    int y = (t >= d) ? sh[t - d] : 0;
    __syncthreads();
    x += y;
    sh[t] = x;
    __syncthreads();
  }
  if (t < nb) {
    bstart[t] = x - v;
    bcur[t] = x - v;
  }
  if (t == 0) bstart[nb] = ne;
}

// ---- pass 1: scatter packed (dst&127,src) into dst-buckets ----
__global__ void __launch_bounds__(256) scatter_kernel(const int* __restrict__ ei,
                                                      int* __restrict__ bcur,
                                                      unsigned* __restrict__ buf,
                                                      int ne, int nb, int epb) {
  __shared__ int lh[NB_MAX], lbs[NB_MAX];
  int t = threadIdx.x;
  for (int i = t; i < nb; i += 256) lh[i] = 0;
  __syncthreads();
  int r0 = blockIdx.x * epb;
  int r1 = min(r0 + epb, ne);
  for (int k = r0 + t; k < r1; k += 256) atomicAdd(&lh[ei[ne + k] >> 7], 1);
  __syncthreads();
  for (int i = t; i < nb; i += 256) {
    int c = lh[i];
    lbs[i] = c ? atomicAdd(&bcur[i], c) : 0;
    lh[i] = 0;  // reuse as local cursor
  }
  __syncthreads();
  for (int k = r0 + t; k < r1; k += 256) {
    int src = ei[k];
    int dst = ei[ne + k];
    int b = dst >> 7;
    int p = lbs[b] + atomicAdd(&lh[b], 1);
    buf[p] = (unsigned)src | ((unsigned)(dst & 127) << 25);
  }
}

// ---- pass 2: one block per bucket: count -> pad4 scan -> offend/dis/csr ----
__global__ void __launch_bounds__(256) bucket_build_kernel(const unsigned* __restrict__ buf,
                                                           const int* __restrict__ bstart,
                                                           int2* __restrict__ offend,
                                                           int* __restrict__ csr,
                                                           float* __restrict__ dis, int n) {
  __shared__ int cnt[128], cur[128], sh[128], ps[128];
  int b = blockIdx.x, t = threadIdx.x;
  int e0 = bstart[b], e1 = bstart[b + 1];
  int pb = ((e0 + 7) & ~7) + 1024 * b;  // padded 8-aligned bucket base
  if (t < 128) cnt[t] = 0;
  __syncthreads();
  for (int k = e0 + t; k < e1; k += 256) atomicAdd(&cnt[buf[k] >> 25], 1);
  __syncthreads();
  int v = 0, pdv = 0;
  if (t < 128) {
    v = cnt[t];
    pdv = (v + 3) & ~3;
    sh[t] = pdv;
  }
  __syncthreads();
  int x = pdv;
  for (int d = 1; d < 128; d <<= 1) {
    int y = (t < 128 && t >= d) ? sh[t - d] : 0;
    __syncthreads();
    if (t < 128) {
      x += y;
      sh[t] = x;
    }
    __syncthreads();
  }
  if (t < 128) {
    int node = (b << 7) + t;
    int st = x - pdv;  // local padded exclusive start (4-aligned)
    ps[t] = st;
    cur[t] = st;
    if (node < n) {
      offend[node] = make_int2(pb + st, pb + st + v);
      dis[node] = rsqrtf((float)(v + 1));
    }
  }
  __syncthreads();
  for (int k = e0 + t; k < e1; k += 256) {
    unsigned u = buf[k];
    int d = u >> 25;
    int p = atomicAdd(&cur[d], 1);
    csr[pb + p] = (int)(u & 0x1FFFFFFu);
  }
  __syncthreads();
  // fill padding slots with sentinel (zero-row index n)
  if (t < 128) {
    int pd = (cnt[t] + 3) & ~3;
    for (int q = cnt[t]; q < pd; ++q) csr[pb + ps[t] + q] = n;
  }
}

// layer 0: HQ(f16, quarter-major) = (X @ W) * dis[row] via MFMA
__global__ void __launch_bounds__(256) gemm_mfma_kernel(const float* __restrict__ Xf,
                                                        const _Float16* __restrict__ Wt,
                                                        const float* __restrict__ dis,
                                                        uint4* __restrict__ H4, int n) {
  __shared__ _Float16 st[64 * FEAT];  // 16 KB epilogue staging
  int tid = threadIdx.x;
  int w = tid >> 6, lane = tid & 63;
  int l15 = lane & 15, hi = lane >> 4;

  int rowA = blockIdx.x * 64 + w * 16 + l15;
  int rA = min(rowA, n - 1);

  f4 acc[8];
#pragma unroll
  for (int nb = 0; nb < 8; ++nb) acc[nb] = (f4)(0.f);

#pragma unroll
  for (int kk = 0; kk < FEAT; kk += 32) {
    int ko = kk + hi * 8;
    h8 a;
    float4 x0 = *(const float4*)&Xf[(size_t)rA * FEAT + ko];
    float4 x1 = *(const float4*)&Xf[(size_t)rA * FEAT + ko + 4];
    a[0] = (_Float16)x0.x; a[1] = (_Float16)x0.y; a[2] = (_Float16)x0.z; a[3] = (_Float16)x0.w;
    a[4] = (_Float16)x1.x; a[5] = (_Float16)x1.y; a[6] = (_Float16)x1.z; a[7] = (_Float16)x1.w;
#pragma unroll
    for (int nb = 0; nb < 8; ++nb) {
      h8 bfr = *(const h8*)&Wt[(nb * 16 + l15) * FEAT + ko];
      acc[nb] = __builtin_amdgcn_mfma_f32_16x16x32_f16(a, bfr, acc[nb], 0, 0, 0);
    }
  }

  float dv[4];
#pragma unroll
  for (int r = 0; r < 4; ++r) {
    int grow = blockIdx.x * 64 + w * 16 + hi * 4 + r;
    dv[r] = dis[min(grow, n - 1)];
  }
#pragma unroll
  for (int nb = 0; nb < 8; ++nb)
#pragma unroll
    for (int r = 0; r < 4; ++r)
      st[(w * 16 + hi * 4 + r) * FEAT + nb * 16 + l15] = (_Float16)(acc[nb][r] * dv[r]);
  __syncthreads();

  int rowbase = blockIdx.x * 64;
  int qs4 = (n + 1) * 4;  // uint4 stride per quarter
#pragma unroll
  for (int i = tid; i < 64 * 16; i += 256) {
    int row = rowbase + (i >> 4);
    int c = i & 15, q = c >> 2;
    if (row < n)
      H4[(size_t)q * qs4 + row * 4 + (c & 3)] = *(const uint4*)&st[(i >> 4) * FEAT + c * 8];
  }
}

// Fused: per node A = relu(dis*agg(HQin)+b), quarter-pass gather (q outermost,
// 3.2 MB hot slice), A-tile in swizzled LDS, then Hs_out = (A @ W)*dis via MFMA.
// 512 thr / 8 waves / 64 rows; phase 1 = 32 groups x 2 nodes, 4-deep gather.
__global__ void __launch_bounds__(512, 6) fused_kernel(const unsigned* __restrict__ HQin,
                                                       const int* __restrict__ csr,
                                                       const int2* __restrict__ offend,
                                                       const float* __restrict__ dis,
                                                       const float* __restrict__ bias,
                                                       const _Float16* __restrict__ Wt,
                                                       uint4* __restrict__ H4out, int n) {
  __shared__ char xsb[64 * 256];  // 16 KB: A-tile, then reused as epilogue staging
  int tid = threadIdx.x;
  int w = tid >> 6, lane = tid & 63;
  int grp = lane >> 4, lig = lane & 15;
  int row0 = blockIdx.x * 64;
  int g32 = w * 4 + grp;  // 0..31

  int nds[2];
  int2 oes[2];
  float ds[2];
#pragma unroll
  for (int m = 0; m < 2; ++m) {
    nds[m] = min(row0 + g32 * 2 + m, n - 1);
    oes[m] = offend[nds[m]];
    ds[m] = dis[nds[m]];
  }
  int qstep = (n + 1) * 16;  // uint stride per quarter

  // ---- phase 1: 4 quarter passes ----
  for (int q = 0; q < 4; ++q) {
    const unsigned* T = HQin + (size_t)q * qstep;
    float2 bq = ((const float2*)bias)[q * 16 + lig];
#pragma unroll
    for (int m = 0; m < 2; ++m) {
      int nd = nds[m];
      float2 sv = uh2f2(T[(size_t)nd * 16 + lig]);  // self-loop
      float ax = sv.x, ay = sv.y, bx = 0.f, by = 0.f;
      int s = oes[m].x;
      int ep = s + ((oes[m].y - s + 3) & ~3);
      for (int k = s; k < ep; k += 4) {
        int4 c = *(const int4*)&csr[k];
        unsigned u0 = T[(size_t)c.x * 16 + lig];
        unsigned u1 = T[(size_t)c.y * 16 + lig];
        unsigned u2 = T[(size_t)c.z * 16 + lig];
        unsigned u3 = T[(size_t)c.w * 16 + lig];
        float2 v0 = uh2f2(u0), v1 = uh2f2(u1), v2 = uh2f2(u2), v3 = uh2f2(u3);
        ax += v0.x; ay += v0.y;
        bx += v1.x; by += v1.y;
        ax += v2.x; ay += v2.y;
        bx += v3.x; by += v3.y;
      }
      float ox = fmaxf(fmaf(ds[m], ax + bx, bq.x), 0.f);
      float oy = fmaxf(fmaf(ds[m], ay + by, bq.y), 0.f);
      __half2 hv = __floats2half2_rn(ox, oy);
      int ar = g32 * 2 + m;
      *(unsigned*)(xsb + swz(ar, q * 64 + lig * 4)) = *(unsigned*)&hv;
    }
  }
  __syncthreads();

  // ---- phase 2: MFMA from LDS A-tile; wave = (strip = w&3, colhalf = w>>2) ----
  int l15 = lane & 15, hi = lane >> 4;
  int strip = w & 3, ch = w >> 2;
  f4 acc[4];
#pragma unroll
  for (int nb = 0; nb < 4; ++nb) acc[nb] = (f4)(0.f);
#pragma unroll
  for (int kk = 0; kk < FEAT; kk += 32) {
    int ko = kk + hi * 8;
    h8 a = *(const h8*)(xsb + swz(strip * 16 + l15, ko * 2));
#pragma unroll
    for (int nb = 0; nb < 4; ++nb) {
      h8 bfr = *(const h8*)&Wt[(ch * 64 + nb * 16 + l15) * FEAT + ko];
      acc[nb] = __builtin_amdgcn_mfma_f32_16x16x32_f16(a, bfr, acc[nb], 0, 0, 0);
    }
  }

  float dv[4];
#pragma unroll
  for (int r = 0; r < 4; ++r) {
    int grow = row0 + strip * 16 + hi * 4 + r;
    dv[r] = dis[min(grow, n - 1)];
  }
  __syncthreads();  // all A-reads done before reusing xsb as staging
#pragma unroll
  for (int nb = 0; nb < 4; ++nb)
#pragma unroll
    for (int r = 0; r < 4; ++r) {
      int srow = strip * 16 + hi * 4 + r;
      *(_Float16*)(xsb + swz(srow, (ch * 64 + nb * 16 + l15) * 2)) =
          (_Float16)(acc[nb][r] * dv[r]);
    }
  __syncthreads();
  int qs4 = (n + 1) * 4;
#pragma unroll
  for (int i = tid; i < 64 * 16; i += 512) {
    int row = row0 + (i >> 4);
    int c = i & 15, q = c >> 2;
    if (row < n)
      H4out[(size_t)q * qs4 + row * 4 + (c & 3)] =
          *(const uint4*)(xsb + swz(i >> 4, c * 16));
  }
}

// Layer-2 agg: quarter-pass gather, writes ROW-MAJOR f16 rows for pool.
__global__ void __launch_bounds__(512, 6) agg_kernel(const unsigned* __restrict__ HQin,
                                                     const int* __restrict__ csr,
                                                     const int2* __restrict__ offend,
                                                     const float* __restrict__ dis,
                                                     const float* __restrict__ bias,
                                                     unsigned* __restrict__ out32, int n) {
  int tid = threadIdx.x;
  int g32 = tid >> 4, lig = tid & 15;  // 32 groups x 16 lanes
  int row0 = blockIdx.x * 64;

  int nds[2];
  int2 oes[2];
  float ds[2];
  bool val[2];
#pragma unroll
  for (int m = 0; m < 2; ++m) {
    int node = row0 + g32 * 2 + m;
    val[m] = node < n;
    nds[m] = min(node, n - 1);
    oes[m] = offend[nds[m]];
    ds[m] = dis[nds[m]];
  }
  int qstep = (n + 1) * 16;

  for (int q = 0; q < 4; ++q) {
    const unsigned* T = HQin + (size_t)q * qstep;
    float2 bq = ((const float2*)bias)[q * 16 + lig];
#pragma unroll
    for (int m = 0; m < 2; ++m) {
      int nd = nds[m];
      float2 sv = uh2f2(T[(size_t)nd * 16 + lig]);
      float ax = sv.x, ay = sv.y, bx = 0.f, by = 0.f;
      int s = oes[m].x;
      int ep = s + ((oes[m].y - s + 3) & ~3);
      for (int k = s; k < ep; k += 4) {
        int4 c = *(const int4*)&csr[k];
        unsigned u0 = T[(size_t)c.x * 16 + lig];
        unsigned u1 = T[(size_t)c.y * 16 + lig];
        unsigned u2 = T[(size_t)c.z * 16 + lig];
        unsigned u3 = T[(size_t)c.w * 16 + lig];
        float2 v0 = uh2f2(u0), v1 = uh2f2(u1), v2 = uh2f2(u2), v3 = uh2f2(u3);
        ax += v0.x; ay += v0.y;
        bx += v1.x; by += v1.y;
        ax += v2.x; ay += v2.y;
        bx += v3.x; by += v3.y;
      }
      float ox = fmaxf(fmaf(ds[m], ax + bx, bq.x), 0.f);
      float oy = fmaxf(fmaf(ds[m], ay + by, bq.y), 0.f);
      __half2 hv = __floats2half2_rn(ox, oy);
      if (val[m]) out32[(size_t)nds[m] * 64 + q * 16 + lig] = *(unsigned*)&hv;
    }
  }
}

// mean-pool per graph (f16 row-major input) + linear(128->10) + log_softmax
__global__ void __launch_bounds__(128) pool_kernel(const __half* __restrict__ h,
                                                   const int* __restrict__ gstart,
                                                   const float* __restrict__ lw,
                                                   const float* __restrict__ lb,
                                                   float* __restrict__ out) {
  int g = blockIdx.x;
  int t = threadIdx.x;
  int s = gstart[g];
  int e = gstart[g + 1];
  float a0 = 0.f, a1 = 0.f, a2 = 0.f, a3 = 0.f;
  int i = s;
  for (; i + 4 <= e; i += 4) {
    a0 += __half2float(h[(size_t)i * FEAT + t]);
    a1 += __half2float(h[(size_t)(i + 1) * FEAT + t]);
    a2 += __half2float(h[(size_t)(i + 2) * FEAT + t]);
    a3 += __half2float(h[(size_t)(i + 3) * FEAT + t]);
  }
  for (; i < e; ++i) a0 += __half2float(h[(size_t)i * FEAT + t]);
  float acc = a0 + a1 + a2 + a3;
  float cnt = (float)(e - s);
  float pooled = acc / fmaxf(cnt, 1.f);
  __shared__ float lds[FEAT];
  __shared__ float logits[NCLASS];
  lds[t] = pooled;
  __syncthreads();
  if (t < NCLASS) {
    float z = lb[t];
    for (int k = 0; k < FEAT; ++k) z += lds[k] * lw[k * NCLASS + t];
    logits[t] = z;
  }
  __syncthreads();
  if (t < NCLASS) {
    float m = logits[0];
#pragma unroll
    for (int c = 1; c < NCLASS; ++c) m = fmaxf(m, logits[c]);
    float ssum = 0.f;
#pragma unroll
    for (int c = 0; c < NCLASS; ++c) ssum += expf(logits[c] - m);
    out[(size_t)g * NCLASS + t] = logits[t] - m - logf(ssum);
  }
}

extern "C" void kernel_launch(void* const* d_in, const int* in_sizes, int n_in,
                              void* d_out, int out_size, void* d_ws, size_t ws_size,
                              hipStream_t stream) {
  const float* x = (const float*)d_in[0];
  const int* ei = (const int*)d_in[1];
  const int* batch = (const int*)d_in[2];
  const float* W0 = (const float*)d_in[3];
  const float* b0 = (const float*)d_in[4];
  const float* W1 = (const float*)d_in[5];
  const float* b1 = (const float*)d_in[6];
  const float* W2 = (const float*)d_in[7];
  const float* b2 = (const float*)d_in[8];
  const float* lw = (const float*)d_in[9];
  const float* lb = (const float*)d_in[10];

  int n = in_sizes[2];        // 50000 nodes
  int ne = in_sizes[1] / 2;   // 800000 edges
  int g = out_size / NCLASS;  // 512 graphs
  int nb = (n + 127) >> 7;    // dst buckets (391)
  int hblocks = 120;
  int epb = (ne + hblocks - 1) / hblocks;
  int wtblocks = (3 * FEAT * FEAT + 255) / 256;  // 192
  int bndblocks = (n + 255) / 256;
  int prep_total = hblocks + wtblocks + bndblocks + 1;  // +1 sentinel block

  char* ws = (char*)d_ws;
  size_t p = 0;
  auto alloc = [&](size_t bytes) {
    size_t cur = p;
    p += (bytes + 255) & ~(size_t)255;
    return cur;
  };
  int2* offend = (int2*)(ws + alloc((size_t)n * 8));
  int* csr = (int*)(ws + alloc(((size_t)ne + 1024 * nb + 64) * 4));
  int* bhist = (int*)(ws + alloc((size_t)NB_MAX * 4));
  int* bstart = (int*)(ws + alloc((size_t)(NB_MAX + 1) * 4));
  int* bcur = (int*)(ws + alloc((size_t)NB_MAX * 4));
  int* gstart = (int*)(ws + alloc((size_t)(g + 1) * 4));
  float* dis = (float*)(ws + alloc((size_t)n * 4));
  unsigned* buf = (unsigned*)(ws + alloc((size_t)ne * 4));
  _Float16* Wt = (_Float16*)(ws + alloc((size_t)3 * FEAT * FEAT * 2));
  unsigned* HQA = (unsigned*)(ws + alloc((size_t)(n + 1) * FEAT * 2));  // quarter-major
  unsigned* HQB = (unsigned*)(ws + alloc((size_t)(n + 1) * FEAT * 2));
  unsigned* HR = (unsigned*)(ws + alloc((size_t)n * FEAT * 2));  // row-major pool input

  hipMemsetAsync(bhist, 0, NB_MAX * 4, stream);

  prep_kernel<<<prep_total, 256, 0, stream>>>(ei, bhist, ne, nb, epb, hblocks, W0, W1, W2,
                                              Wt, wtblocks, batch, gstart, n, g, HQA, HQB,
                                              prep_total);
  bscan_kernel<<<1, 512, 0, stream>>>(bhist, bstart, bcur, nb, ne);
  scatter_kernel<<<hblocks, 256, 0, stream>>>(ei, bcur, buf, ne, nb, epb);
  bucket_build_kernel<<<nb, 256, 0, stream>>>(buf, bstart, offend, csr, dis, n);

  int gblocks = (n + 63) / 64;
  // layer 0: X(f32) @ W0 * dis -> HQA (quarter-major)
  gemm_mfma_kernel<<<gblocks, 256, 0, stream>>>(x, Wt, dis, (uint4*)HQA, n);
  // layer 0 agg + layer 1 gemm: HQA -> HQB
  fused_kernel<<<gblocks, 512, 0, stream>>>(HQA, csr, offend, dis, b0,
                                            Wt + (size_t)1 * FEAT * FEAT, (uint4*)HQB, n);
  // layer 1 agg + layer 2 gemm: HQB -> HQA
  fused_kernel<<<gblocks, 512, 0, stream>>>(HQB, csr, offend, dis, b1,
                                            Wt + (size_t)2 * FEAT * FEAT, (uint4*)HQA, n);
  // layer 2 agg: HQA -> HR (row-major pool input)
  agg_kernel<<<gblocks, 512, 0, stream>>>(HQA, csr, offend, dis, b2, HR, n);

  pool_kernel<<<g, 128, 0, stream>>>((const __half*)HR, gstart, lw, lb, (float*)d_out);
}

// Round 13
// 219.681 us; speedup vs baseline: 1.0841x; 1.0841x over previous
//
#include <hip/hip_runtime.h>
#include <hip/hip_fp16.h>

// GCN forward: 3x (MFMA GEMM + normalized adjacency aggregate + ReLU) + mean-pool + linear + log_softmax
// N=50000, E=800000, F=H=128, C=10, G=512
// Round 13: src-chunked gather. Each node's edges sorted by src/12500 (4 chunks,
// 3.2 MB of rows each = per-XCD-L2-resident); phase 1 loops chunks outermost with
// a block barrier, f32 accumulators persist in registers. csr read once, 16B/lane
// h8 loads (unlike r12's failed feature-quartering). Sub-segments pad4'd with
// sentinel row n.

#define FEAT 128
#define NCLASS 10
#define NB_MAX 512  // max dst buckets (n <= 65536 here: 391)

typedef _Float16 h8 __attribute__((ext_vector_type(8)));
typedef float f4 __attribute__((ext_vector_type(4)));

// LDS tile swizzle: row stride 256B; XOR row&7 into byte bits 4..6.
__device__ inline int swz(int row, int cbyte) { return row * 256 + (cbyte ^ ((row & 7) << 4)); }

// ---- pass 0 combined: bucket histogram (blocks <hb) + Wt convert + bounds ----
__global__ void __launch_bounds__(256) prep_kernel(const int* __restrict__ ei,
                                                   int* __restrict__ bhist,
                                                   int ne, int nb, int epb, int hb,
                                                   const float* __restrict__ W0,
                                                   const float* __restrict__ W1,
                                                   const float* __restrict__ W2,
                                                   _Float16* __restrict__ Wt, int wtb,
                                                   const int* __restrict__ batch,
                                                   int* __restrict__ gstart, int n, int g) {
  int t = threadIdx.x;
  if (blockIdx.x >= hb + wtb) {
    // graph boundaries from sorted batch
    int i = (blockIdx.x - hb - wtb) * 256 + t;
    if (i >= n) return;
    int bi = batch[i];
    int bp = (i == 0) ? -1 : batch[i - 1];
    for (int q = bp + 1; q <= bi; ++q) gstart[q] = i;
    if (i == n - 1)
      for (int q = bi + 1; q <= g; ++q) gstart[q] = n;
    return;
  }
  if (blockIdx.x >= hb) {
    // Wt[l][n][k] = W_l[k][n]
    int i = (blockIdx.x - hb) * 256 + t;
    if (i < 3 * FEAT * FEAT) {
      int l = i / (FEAT * FEAT);
      int r = i - l * (FEAT * FEAT);
      int nn = r >> 7, kk = r & 127;
      const float* W = (l == 0) ? W0 : (l == 1) ? W1 : W2;
      Wt[i] = (_Float16)W[kk * FEAT + nn];
    }
    return;
  }
  __shared__ int lh[NB_MAX];
  for (int i = t; i < nb; i += 256) lh[i] = 0;
  __syncthreads();
  int r0 = blockIdx.x * epb;
  int r1 = min(r0 + epb, ne);
  for (int k = r0 + t; k < r1; k += 256) atomicAdd(&lh[ei[ne + k] >> 7], 1);
  __syncthreads();
  for (int i = t; i < nb; i += 256)
    if (lh[i]) atomicAdd(&bhist[i], lh[i]);
}

// ---- exclusive scan of bucket counts -> bstart (kept) and bcur (consumed) ----
__global__ void __launch_bounds__(512) bscan_kernel(const int* __restrict__ bhist,
                                                    int* __restrict__ bstart,
                                                    int* __restrict__ bcur,
                                                    int nb, int ne) {
  __shared__ int sh[512];
  int t = threadIdx.x;
  int v = (t < nb) ? bhist[t] : 0;
  sh[t] = v;
  __syncthreads();
  int x = v;
  for (int d = 1; d < 512; d <<= 1) {
    int y = (t >= d) ? sh[t - d] : 0;
    __syncthreads();
    x += y;
    sh[t] = x;
    __syncthreads();
  }
  if (t < nb) {
    bstart[t] = x - v;
    bcur[t] = x - v;
  }
  if (t == 0) bstart[nb] = ne;
}

// ---- pass 1: scatter packed (dst&127,src) into dst-buckets ----
__global__ void __launch_bounds__(256) scatter_kernel(const int* __restrict__ ei,
                                                      int* __restrict__ bcur,
                                                      unsigned* __restrict__ buf,
                                                      int ne, int nb, int epb) {
  __shared__ int lh[NB_MAX], lbs[NB_MAX];
  int t = threadIdx.x;
  for (int i = t; i < nb; i += 256) lh[i] = 0;
  __syncthreads();
  int r0 = blockIdx.x * epb;
  int r1 = min(r0 + epb, ne);
  for (int k = r0 + t; k < r1; k += 256) atomicAdd(&lh[ei[ne + k] >> 7], 1);
  __syncthreads();
  for (int i = t; i < nb; i += 256) {
    int c = lh[i];
    lbs[i] = c ? atomicAdd(&bcur[i], c) : 0;
    lh[i] = 0;  // reuse as local cursor
  }
  __syncthreads();
  for (int k = r0 + t; k < r1; k += 256) {
    int src = ei[k];
    int dst = ei[ne + k];
    int b = dst >> 7;
    int p = lbs[b] + atomicAdd(&lh[b], 1);
    buf[p] = (unsigned)src | ((unsigned)(dst & 127) << 25);
  }
}

// ---- pass 2: one block per bucket: per-(node,chunk) count -> pad4 scan ->
// off4/oend/dis/csr. Chunk = src/csize (4 chunks). Sub-segments pad4'd with n.
__global__ void __launch_bounds__(256) bucket_build_kernel(const unsigned* __restrict__ buf,
                                                           const int* __restrict__ bstart,
                                                           int4* __restrict__ off4,
                                                           int* __restrict__ oend,
                                                           int* __restrict__ csr,
                                                           float* __restrict__ dis,
                                                           int n, int csize) {
  __shared__ int cnt[512], cur[512], loc[512], sh[128];
  int b = blockIdx.x, t = threadIdx.x;
  int e0 = bstart[b], e1 = bstart[b + 1];
  int pb = ((e0 + 7) & ~7) + 2048 * b;  // padded bucket base (pad <= 12/node)
  for (int i = t; i < 512; i += 256) cnt[i] = 0;
  __syncthreads();
  for (int k = e0 + t; k < e1; k += 256) {
    unsigned u = buf[k];
    int src = (int)(u & 0x1FFFFFFu);
    int d = u >> 25;
    int c = (src >= 3 * csize) ? 3 : (src >= 2 * csize) ? 2 : (src >= csize) ? 1 : 0;
    atomicAdd(&cnt[d * 4 + c], 1);
  }
  __syncthreads();
  int tot = 0;
  if (t < 128) {
    int p0 = (cnt[t * 4 + 0] + 3) & ~3;
    int p1 = (cnt[t * 4 + 1] + 3) & ~3;
    int p2 = (cnt[t * 4 + 2] + 3) & ~3;
    int p3 = (cnt[t * 4 + 3] + 3) & ~3;
    loc[t * 4 + 0] = 0;
    loc[t * 4 + 1] = p0;
    loc[t * 4 + 2] = p0 + p1;
    loc[t * 4 + 3] = p0 + p1 + p2;
    tot = p0 + p1 + p2 + p3;
    sh[t] = tot;
  }
  __syncthreads();
  int x = tot;
  for (int d = 1; d < 128; d <<= 1) {
    int y = (t < 128 && t >= d) ? sh[t - d] : 0;
    __syncthreads();
    if (t < 128) {
      x += y;
      sh[t] = x;
    }
    __syncthreads();
  }
  if (t < 128) {
    int st = pb + x - tot;  // node's padded segment start (4-aligned)
    int node = (b << 7) + t;
    int s0 = st + loc[t * 4 + 0], s1 = st + loc[t * 4 + 1];
    int s2 = st + loc[t * 4 + 2], s3 = st + loc[t * 4 + 3];
    cur[t * 4 + 0] = s0;
    cur[t * 4 + 1] = s1;
    cur[t * 4 + 2] = s2;
    cur[t * 4 + 3] = s3;
    if (node < n) {
      off4[node] = make_int4(s0, s1, s2, s3);
      oend[node] = st + tot;
      int v = cnt[t * 4] + cnt[t * 4 + 1] + cnt[t * 4 + 2] + cnt[t * 4 + 3];
      dis[node] = rsqrtf((float)(v + 1));
    }
  }
  __syncthreads();
  for (int k = e0 + t; k < e1; k += 256) {
    unsigned u = buf[k];
    int src = (int)(u & 0x1FFFFFFu);
    int d = u >> 25;
    int c = (src >= 3 * csize) ? 3 : (src >= 2 * csize) ? 2 : (src >= csize) ? 1 : 0;
    int p = atomicAdd(&cur[d * 4 + c], 1);
    csr[p] = src;
  }
  __syncthreads();
  // fill pad slots with sentinel row n (cur now == sub-segment start + cnt)
  if (t < 128) {
#pragma unroll
    for (int c = 0; c < 4; ++c) {
      int k0 = t * 4 + c;
      int pad = ((cnt[k0] + 3) & ~3) - cnt[k0];
      int base = cur[k0];
      for (int q = 0; q < pad; ++q) csr[base + q] = n;
    }
  }
}

// layer 0: Hs(f16 row-major) = (X @ W) * dis[row] via MFMA
__global__ void __launch_bounds__(256) gemm_mfma_kernel(const float* __restrict__ Xf,
                                                        const _Float16* __restrict__ Wt,
                                                        const float* __restrict__ dis,
                                                        _Float16* __restrict__ Hs, int n) {
  __shared__ _Float16 st[64 * FEAT];  // 16 KB epilogue staging
  int tid = threadIdx.x;
  int w = tid >> 6, lane = tid & 63;
  int l15 = lane & 15, hi = lane >> 4;

  int rowA = blockIdx.x * 64 + w * 16 + l15;
  int rA = min(rowA, n - 1);

  f4 acc[8];
#pragma unroll
  for (int nb = 0; nb < 8; ++nb) acc[nb] = (f4)(0.f);

#pragma unroll
  for (int kk = 0; kk < FEAT; kk += 32) {
    int ko = kk + hi * 8;
    h8 a;
    float4 x0 = *(const float4*)&Xf[(size_t)rA * FEAT + ko];
    float4 x1 = *(const float4*)&Xf[(size_t)rA * FEAT + ko + 4];
    a[0] = (_Float16)x0.x; a[1] = (_Float16)x0.y; a[2] = (_Float16)x0.z; a[3] = (_Float16)x0.w;
    a[4] = (_Float16)x1.x; a[5] = (_Float16)x1.y; a[6] = (_Float16)x1.z; a[7] = (_Float16)x1.w;
#pragma unroll
    for (int nb = 0; nb < 8; ++nb) {
      h8 bfr = *(const h8*)&Wt[(nb * 16 + l15) * FEAT + ko];
      acc[nb] = __builtin_amdgcn_mfma_f32_16x16x32_f16(a, bfr, acc[nb], 0, 0, 0);
    }
  }

  float dv[4];
#pragma unroll
  for (int r = 0; r < 4; ++r) {
    int grow = blockIdx.x * 64 + w * 16 + hi * 4 + r;
    dv[r] = dis[min(grow, n - 1)];
  }
#pragma unroll
  for (int nb = 0; nb < 8; ++nb)
#pragma unroll
    for (int r = 0; r < 4; ++r)
      st[(w * 16 + hi * 4 + r) * FEAT + nb * 16 + l15] = (_Float16)(acc[nb][r] * dv[r]);
  __syncthreads();

  int rowbase = blockIdx.x * 64;
#pragma unroll
  for (int i = tid; i < 64 * FEAT / 8; i += 256) {
    int row = rowbase + (i >> 4);
    if (row < n)
      *(uint4*)&Hs[(size_t)row * FEAT + (i & 15) * 8] =
          *(const uint4*)&st[(i >> 4) * FEAT + (i & 15) * 8];
  }
}

// Fused: A = relu(dis*agg(Hs_in) + b_prev) per node (64 nodes -> swizzled LDS
// tile), then Hs_out = (A @ W) * dis via MFMA. 512 thr / 8 waves / 64 rows.
// Phase 1: chunk-outermost gather (4 chunks, block barrier per chunk);
// 32 groups x 2 nodes; 4-deep h8 loads; acc persists in registers.
__global__ void __launch_bounds__(512, 6) fused_kernel(const h8* __restrict__ Hs_in,
                                                       const int* __restrict__ csr,
                                                       const int4* __restrict__ off4,
                                                       const int* __restrict__ oend,
                                                       const float* __restrict__ dis,
                                                       const float* __restrict__ bias,
                                                       const _Float16* __restrict__ Wt,
                                                       _Float16* __restrict__ Hs_out, int n) {
  __shared__ char xsb[64 * 256];  // 16 KB: A-tile, then reused as epilogue staging
  int tid = threadIdx.x;
  int w = tid >> 6, lane = tid & 63;
  int grp = lane >> 4, lig = lane & 15;
  int row0 = blockIdx.x * 64;
  int g32 = w * 4 + grp;  // 0..31

  int nd0 = min(row0 + g32 * 2, n - 1);
  int nd1 = min(row0 + g32 * 2 + 1, n - 1);
  int4 o0 = off4[nd0], o1 = off4[nd1];
  int oe0 = oend[nd0], oe1 = oend[nd1];

  float acc0[8], acc1[8];
  h8 sv0 = Hs_in[(size_t)nd0 * 16 + lig];
  h8 sv1 = Hs_in[(size_t)nd1 * 16 + lig];
#pragma unroll
  for (int j = 0; j < 8; ++j) {
    acc0[j] = (float)sv0[j];
    acc1[j] = (float)sv1[j];
  }

  // ---- phase 1: chunk-outermost gather (hot slice = 3.2 MB, L2-resident) ----
#pragma unroll
  for (int c = 0; c < 4; ++c) {
    int s0 = (c == 0) ? o0.x : (c == 1) ? o0.y : (c == 2) ? o0.z : o0.w;
    int e0 = (c == 0) ? o0.y : (c == 1) ? o0.z : (c == 2) ? o0.w : oe0;
    for (int k = s0; k < e0; k += 4) {
      int4 ci = *(const int4*)&csr[k];
      h8 v0 = Hs_in[(size_t)ci.x * 16 + lig];
      h8 v1 = Hs_in[(size_t)ci.y * 16 + lig];
      h8 v2 = Hs_in[(size_t)ci.z * 16 + lig];
      h8 v3 = Hs_in[(size_t)ci.w * 16 + lig];
#pragma unroll
      for (int j = 0; j < 8; ++j)
        acc0[j] += ((float)v0[j] + (float)v1[j]) + ((float)v2[j] + (float)v3[j]);
    }
    int s1 = (c == 0) ? o1.x : (c == 1) ? o1.y : (c == 2) ? o1.z : o1.w;
    int e1 = (c == 0) ? o1.y : (c == 1) ? o1.z : (c == 2) ? o1.w : oe1;
    for (int k = s1; k < e1; k += 4) {
      int4 ci = *(const int4*)&csr[k];
      h8 v0 = Hs_in[(size_t)ci.x * 16 + lig];
      h8 v1 = Hs_in[(size_t)ci.y * 16 + lig];
      h8 v2 = Hs_in[(size_t)ci.z * 16 + lig];
      h8 v3 = Hs_in[(size_t)ci.w * 16 + lig];
#pragma unroll
      for (int j = 0; j < 8; ++j)
        acc1[j] += ((float)v0[j] + (float)v1[j]) + ((float)v2[j] + (float)v3[j]);
    }
    __syncthreads();  // keep block's waves chunk-aligned
  }

  // epilogue of phase 1: bias + dis + relu -> swizzled LDS A-tile
  float d0 = dis[nd0], d1 = dis[nd1];
  float4 bb0 = ((const float4*)bias)[lig * 2];
  float4 bb1 = ((const float4*)bias)[lig * 2 + 1];
  float bb[8] = {bb0.x, bb0.y, bb0.z, bb0.w, bb1.x, bb1.y, bb1.z, bb1.w};
  h8 oA, oB;
#pragma unroll
  for (int j = 0; j < 8; ++j) {
    oA[j] = (_Float16)fmaxf(fmaf(d0, acc0[j], bb[j]), 0.f);
    oB[j] = (_Float16)fmaxf(fmaf(d1, acc1[j], bb[j]), 0.f);
  }
  *(h8*)(xsb + swz(g32 * 2, lig * 16)) = oA;
  *(h8*)(xsb + swz(g32 * 2 + 1, lig * 16)) = oB;
  __syncthreads();

  // ---- phase 2: MFMA from LDS A-tile; wave = (strip = w&3, colhalf = w>>2) ----
  int l15 = lane & 15, hi = lane >> 4;
  int strip = w & 3, ch = w >> 2;
  f4 acc[4];
#pragma unroll
  for (int nb = 0; nb < 4; ++nb) acc[nb] = (f4)(0.f);
#pragma unroll
  for (int kk = 0; kk < FEAT; kk += 32) {
    int ko = kk + hi * 8;
    h8 a = *(const h8*)(xsb + swz(strip * 16 + l15, ko * 2));
#pragma unroll
    for (int nb = 0; nb < 4; ++nb) {
      h8 bfr = *(const h8*)&Wt[(ch * 64 + nb * 16 + l15) * FEAT + ko];
      acc[nb] = __builtin_amdgcn_mfma_f32_16x16x32_f16(a, bfr, acc[nb], 0, 0, 0);
    }
  }

  float dv[4];
#pragma unroll
  for (int r = 0; r < 4; ++r) {
    int grow = row0 + strip * 16 + hi * 4 + r;
    dv[r] = dis[min(grow, n - 1)];
  }
  __syncthreads();  // all A-reads done before reusing xsb as staging
#pragma unroll
  for (int nb = 0; nb < 4; ++nb)
#pragma unroll
    for (int r = 0; r < 4; ++r) {
      int srow = strip * 16 + hi * 4 + r;
      *(_Float16*)(xsb + swz(srow, (ch * 64 + nb * 16 + l15) * 2)) =
          (_Float16)(acc[nb][r] * dv[r]);
    }
  __syncthreads();
#pragma unroll
  for (int i = tid; i < 64 * FEAT / 8; i += 512) {
    int row = row0 + (i >> 4);
    if (row < n)
      *(uint4*)&Hs_out[(size_t)row * FEAT + (i & 15) * 8] =
          *(const uint4*)(xsb + swz(i >> 4, (i & 15) * 16));
  }
}

// Layer-2 agg standalone: chunk-outermost gather, writes h8 rows for pool.
__global__ void __launch_bounds__(512, 6) agg_kernel(const h8* __restrict__ Hs,
                                                     const int* __restrict__ csr,
                                                     const int4* __restrict__ off4,
                                                     const int* __restrict__ oend,
                                                     const float* __restrict__ dis,
                                                     const float* __restrict__ bias,
                                                     h8* __restrict__ out, int n) {
  int tid = threadIdx.x;
  int g32 = tid >> 4, lig = tid & 15;  // 32 groups x 16 lanes
  int row0 = blockIdx.x * 64;

  int node0 = row0 + g32 * 2, node1 = node0 + 1;
  int nd0 = min(node0, n - 1), nd1 = min(node1, n - 1);
  int4 o0 = off4[nd0], o1 = off4[nd1];
  int oe0 = oend[nd0], oe1 = oend[nd1];

  float acc0[8], acc1[8];
  h8 sv0 = Hs[(size_t)nd0 * 16 + lig];
  h8 sv1 = Hs[(size_t)nd1 * 16 + lig];
#pragma unroll
  for (int j = 0; j < 8; ++j) {
    acc0[j] = (float)sv0[j];
    acc1[j] = (float)sv1[j];
  }

#pragma unroll
  for (int c = 0; c < 4; ++c) {
    int s0 = (c == 0) ? o0.x : (c == 1) ? o0.y : (c == 2) ? o0.z : o0.w;
    int e0 = (c == 0) ? o0.y : (c == 1) ? o0.z : (c == 2) ? o0.w : oe0;
    for (int k = s0; k < e0; k += 4) {
      int4 ci = *(const int4*)&csr[k];
      h8 v0 = Hs[(size_t)ci.x * 16 + lig];
      h8 v1 = Hs[(size_t)ci.y * 16 + lig];
      h8 v2 = Hs[(size_t)ci.z * 16 + lig];
      h8 v3 = Hs[(size_t)ci.w * 16 + lig];
#pragma unroll
      for (int j = 0; j < 8; ++j)
        acc0[j] += ((float)v0[j] + (float)v1[j]) + ((float)v2[j] + (float)v3[j]);
    }
    int s1 = (c == 0) ? o1.x : (c == 1) ? o1.y : (c == 2) ? o1.z : o1.w;
    int e1 = (c == 0) ? o1.y : (c == 1) ? o1.z : (c == 2) ? o1.w : oe1;
    for (int k = s1; k < e1; k += 4) {
      int4 ci = *(const int4*)&csr[k];
      h8 v0 = Hs[(size_t)ci.x * 16 + lig];
      h8 v1 = Hs[(size_t)ci.y * 16 + lig];
      h8 v2 = Hs[(size_t)ci.z * 16 + lig];
      h8 v3 = Hs[(size_t)ci.w * 16 + lig];
#pragma unroll
      for (int j = 0; j < 8; ++j)
        acc1[j] += ((float)v0[j] + (float)v1[j]) + ((float)v2[j] + (float)v3[j]);
    }
    __syncthreads();
  }

  float d0 = dis[nd0], d1 = dis[nd1];
  float4 bb0 = ((const float4*)bias)[lig * 2];
  float4 bb1 = ((const float4*)bias)[lig * 2 + 1];
  float bb[8] = {bb0.x, bb0.y, bb0.z, bb0.w, bb1.x, bb1.y, bb1.z, bb1.w};
  h8 oA, oB;
#pragma unroll
  for (int j = 0; j < 8; ++j) {
    oA[j] = (_Float16)fmaxf(fmaf(d0, acc0[j], bb[j]), 0.f);
    oB[j] = (_Float16)fmaxf(fmaf(d1, acc1[j], bb[j]), 0.f);
  }
  if (node0 < n) out[(size_t)node0 * 16 + lig] = oA;
  if (node1 < n) out[(size_t)node1 * 16 + lig] = oB;
}

// mean-pool per graph (f16 input) + linear(128->10) + log_softmax
__global__ void __launch_bounds__(128) pool_kernel(const __half* __restrict__ h,
                                                   const int* __restrict__ gstart,
                                                   const float* __restrict__ lw,
                                                   const float* __restrict__ lb,
                                                   float* __restrict__ out) {
  int g = blockIdx.x;
  int t = threadIdx.x;
  int s = gstart[g];
  int e = gstart[g + 1];
  float a0 = 0.f, a1 = 0.f, a2 = 0.f, a3 = 0.f;
  int i = s;
  for (; i + 4 <= e; i += 4) {
    a0 += __half2float(h[(size_t)i * FEAT + t]);
    a1 += __half2float(h[(size_t)(i + 1) * FEAT + t]);
    a2 += __half2float(h[(size_t)(i + 2) * FEAT + t]);
    a3 += __half2float(h[(size_t)(i + 3) * FEAT + t]);
  }
  for (; i < e; ++i) a0 += __half2float(h[(size_t)i * FEAT + t]);
  float acc = a0 + a1 + a2 + a3;
  float cnt = (float)(e - s);
  float pooled = acc / fmaxf(cnt, 1.f);
  __shared__ float lds[FEAT];
  __shared__ float logits[NCLASS];
  lds[t] = pooled;
  __syncthreads();
  if (t < NCLASS) {
    float z = lb[t];
    for (int k = 0; k < FEAT; ++k) z += lds[k] * lw[k * NCLASS + t];
    logits[t] = z;
  }
  __syncthreads();
  if (t < NCLASS) {
    float m = logits[0];
#pragma unroll
    for (int c = 1; c < NCLASS; ++c) m = fmaxf(m, logits[c]);
    float ssum = 0.f;
#pragma unroll
    for (int c = 0; c < NCLASS; ++c) ssum += expf(logits[c] - m);
    out[(size_t)g * NCLASS + t] = logits[t] - m - logf(ssum);
  }
}

extern "C" void kernel_launch(void* const* d_in, const int* in_sizes, int n_in,
                              void* d_out, int out_size, void* d_ws, size_t ws_size,
                              hipStream_t stream) {
  const float* x = (const float*)d_in[0];
  const int* ei = (const int*)d_in[1];
  const int* batch = (const int*)d_in[2];
  const float* W0 = (const float*)d_in[3];
  const float* b0 = (const float*)d_in[4];
  const float* W1 = (const float*)d_in[5];
  const float* b1 = (const float*)d_in[6];
  const float* W2 = (const float*)d_in[7];
  const float* b2 = (const float*)d_in[8];
  const float* lw = (const float*)d_in[9];
  const float* lb = (const float*)d_in[10];

  int n = in_sizes[2];        // 50000 nodes
  int ne = in_sizes[1] / 2;   // 800000 edges
  int g = out_size / NCLASS;  // 512 graphs
  int nb = (n + 127) >> 7;    // dst buckets (391)
  int csize = (n + 3) / 4;    // src chunk size (12500)
  int hblocks = 120;
  int epb = (ne + hblocks - 1) / hblocks;
  int wtblocks = (3 * FEAT * FEAT + 255) / 256;  // 192
  int bndblocks = (n + 255) / 256;

  char* ws = (char*)d_ws;
  size_t p = 0;
  auto alloc = [&](size_t bytes) {
    size_t cur = p;
    p += (bytes + 255) & ~(size_t)255;
    return cur;
  };
  int4* off4 = (int4*)(ws + alloc((size_t)n * 16));
  int* oend = (int*)(ws + alloc((size_t)n * 4));
  int* csr = (int*)(ws + alloc(((size_t)ne + 2048 * (size_t)nb + 64) * 4));
  int* bhist = (int*)(ws + alloc((size_t)NB_MAX * 4));
  int* bstart = (int*)(ws + alloc((size_t)(NB_MAX + 1) * 4));
  int* bcur = (int*)(ws + alloc((size_t)NB_MAX * 4));
  int* gstart = (int*)(ws + alloc((size_t)(g + 1) * 4));
  float* dis = (float*)(ws + alloc((size_t)n * 4));
  unsigned* buf = (unsigned*)(ws + alloc((size_t)ne * 4));
  _Float16* Wt = (_Float16*)(ws + alloc((size_t)3 * FEAT * FEAT * 2));
  _Float16* HA = (_Float16*)(ws + alloc((size_t)(n + 1) * FEAT * 2));  // +1 zero row
  _Float16* HB = (_Float16*)(ws + alloc((size_t)(n + 1) * FEAT * 2));

  hipMemsetAsync(bhist, 0, NB_MAX * 4, stream);
  hipMemsetAsync(HA + (size_t)n * FEAT, 0, FEAT * 2, stream);  // sentinel zero rows
  hipMemsetAsync(HB + (size_t)n * FEAT, 0, FEAT * 2, stream);

  prep_kernel<<<hblocks + wtblocks + bndblocks, 256, 0, stream>>>(
      ei, bhist, ne, nb, epb, hblocks, W0, W1, W2, Wt, wtblocks, batch, gstart, n, g);
  bscan_kernel<<<1, 512, 0, stream>>>(bhist, bstart, bcur, nb, ne);
  scatter_kernel<<<hblocks, 256, 0, stream>>>(ei, bcur, buf, ne, nb, epb);
  bucket_build_kernel<<<nb, 256, 0, stream>>>(buf, bstart, off4, oend, csr, dis, n, csize);

  int gblocks = (n + 63) / 64;
  // layer 0: X(f32) @ W0 * dis -> HA
  gemm_mfma_kernel<<<gblocks, 256, 0, stream>>>(x, Wt, dis, HA, n);
  // layer 0 agg + layer 1 gemm: HA -> HB
  fused_kernel<<<gblocks, 512, 0, stream>>>((const h8*)HA, csr, off4, oend, dis, b0,
                                            Wt + (size_t)1 * FEAT * FEAT, HB, n);
  // layer 1 agg + layer 2 gemm: HB -> HA
  fused_kernel<<<gblocks, 512, 0, stream>>>((const h8*)HB, csr, off4, oend, dis, b1,
                                            Wt + (size_t)2 * FEAT * FEAT, HA, n);
  // layer 2 agg: HA -> HB (pool input)
  agg_kernel<<<gblocks, 512, 0, stream>>>((const h8*)HA, csr, off4, oend, dis, b2,
                                          (h8*)HB, n);

  pool_kernel<<<g, 128, 0, stream>>>((const __half*)HB, gstart, lw, lb, (float*)d_out);
}

// Round 14
// 215.214 us; speedup vs baseline: 1.1066x; 1.0208x over previous
//
#include <hip/hip_runtime.h>
#include <hip/hip_fp16.h>

// GCN forward: 3x (MFMA GEMM + normalized adjacency aggregate + ReLU) + mean-pool + linear + log_softmax
// N=50000, E=800000, F=H=128, C=10, G=512
// Round 14: consolidation. Keep r13's chunked fused kernel (48.0 us, best) +
// chunked bucket_build; standalone agg simplified to a single-range branchless
// scan over [off4.x, oend) (contiguous padded range, sentinel row n) — no chunk
// barriers, no per-chunk bookkeeping.

#define FEAT 128
#define NCLASS 10
#define NB_MAX 512  // max dst buckets (n <= 65536 here: 391)

typedef _Float16 h8 __attribute__((ext_vector_type(8)));
typedef float f4 __attribute__((ext_vector_type(4)));

// LDS tile swizzle: row stride 256B; XOR row&7 into byte bits 4..6.
__device__ inline int swz(int row, int cbyte) { return row * 256 + (cbyte ^ ((row & 7) << 4)); }

// ---- pass 0 combined: bucket histogram (blocks <hb) + Wt convert + bounds ----
__global__ void __launch_bounds__(256) prep_kernel(const int* __restrict__ ei,
                                                   int* __restrict__ bhist,
                                                   int ne, int nb, int epb, int hb,
                                                   const float* __restrict__ W0,
                                                   const float* __restrict__ W1,
                                                   const float* __restrict__ W2,
                                                   _Float16* __restrict__ Wt, int wtb,
                                                   const int* __restrict__ batch,
                                                   int* __restrict__ gstart, int n, int g) {
  int t = threadIdx.x;
  if (blockIdx.x >= hb + wtb) {
    // graph boundaries from sorted batch
    int i = (blockIdx.x - hb - wtb) * 256 + t;
    if (i >= n) return;
    int bi = batch[i];
    int bp = (i == 0) ? -1 : batch[i - 1];
    for (int q = bp + 1; q <= bi; ++q) gstart[q] = i;
    if (i == n - 1)
      for (int q = bi + 1; q <= g; ++q) gstart[q] = n;
    return;
  }
  if (blockIdx.x >= hb) {
    // Wt[l][n][k] = W_l[k][n]
    int i = (blockIdx.x - hb) * 256 + t;
    if (i < 3 * FEAT * FEAT) {
      int l = i / (FEAT * FEAT);
      int r = i - l * (FEAT * FEAT);
      int nn = r >> 7, kk = r & 127;
      const float* W = (l == 0) ? W0 : (l == 1) ? W1 : W2;
      Wt[i] = (_Float16)W[kk * FEAT + nn];
    }
    return;
  }
  __shared__ int lh[NB_MAX];
  for (int i = t; i < nb; i += 256) lh[i] = 0;
  __syncthreads();
  int r0 = blockIdx.x * epb;
  int r1 = min(r0 + epb, ne);
  for (int k = r0 + t; k < r1; k += 256) atomicAdd(&lh[ei[ne + k] >> 7], 1);
  __syncthreads();
  for (int i = t; i < nb; i += 256)
    if (lh[i]) atomicAdd(&bhist[i], lh[i]);
}

// ---- exclusive scan of bucket counts -> bstart (kept) and bcur (consumed) ----
__global__ void __launch_bounds__(512) bscan_kernel(const int* __restrict__ bhist,
                                                    int* __restrict__ bstart,
                                                    int* __restrict__ bcur,
                                                    int nb, int ne) {
  __shared__ int sh[512];
  int t = threadIdx.x;
  int v = (t < nb) ? bhist[t] : 0;
  sh[t] = v;
  __syncthreads();
  int x = v;
  for (int d = 1; d < 512; d <<= 1) {
    int y = (t >= d) ? sh[t - d] : 0;
    __syncthreads();
    x += y;
    sh[t] = x;
    __syncthreads();
  }
  if (t < nb) {
    bstart[t] = x - v;
    bcur[t] = x - v;
  }
  if (t == 0) bstart[nb] = ne;
}

// ---- pass 1: scatter packed (dst&127,src) into dst-buckets ----
__global__ void __launch_bounds__(256) scatter_kernel(const int* __restrict__ ei,
                                                      int* __restrict__ bcur,
                                                      unsigned* __restrict__ buf,
                                                      int ne, int nb, int epb) {
  __shared__ int lh[NB_MAX], lbs[NB_MAX];
  int t = threadIdx.x;
  for (int i = t; i < nb; i += 256) lh[i] = 0;
  __syncthreads();
  int r0 = blockIdx.x * epb;
  int r1 = min(r0 + epb, ne);
  for (int k = r0 + t; k < r1; k += 256) atomicAdd(&lh[ei[ne + k] >> 7], 1);
  __syncthreads();
  for (int i = t; i < nb; i += 256) {
    int c = lh[i];
    lbs[i] = c ? atomicAdd(&bcur[i], c) : 0;
    lh[i] = 0;  // reuse as local cursor
  }
  __syncthreads();
  for (int k = r0 + t; k < r1; k += 256) {
    int src = ei[k];
    int dst = ei[ne + k];
    int b = dst >> 7;
    int p = lbs[b] + atomicAdd(&lh[b], 1);
    buf[p] = (unsigned)src | ((unsigned)(dst & 127) << 25);
  }
}

// ---- pass 2: one block per bucket: per-(node,chunk) count -> pad4 scan ->
// off4/oend/dis/csr. Chunk = src/csize (4 chunks). Sub-segments pad4'd with n.
__global__ void __launch_bounds__(256) bucket_build_kernel(const unsigned* __restrict__ buf,
                                                           const int* __restrict__ bstart,
                                                           int4* __restrict__ off4,
                                                           int* __restrict__ oend,
                                                           int* __restrict__ csr,
                                                           float* __restrict__ dis,
                                                           int n, int csize) {
  __shared__ int cnt[512], cur[512], loc[512], sh[128];
  int b = blockIdx.x, t = threadIdx.x;
  int e0 = bstart[b], e1 = bstart[b + 1];
  int pb = ((e0 + 7) & ~7) + 2048 * b;  // padded bucket base (pad <= 12/node)
  for (int i = t; i < 512; i += 256) cnt[i] = 0;
  __syncthreads();
  for (int k = e0 + t; k < e1; k += 256) {
    unsigned u = buf[k];
    int src = (int)(u & 0x1FFFFFFu);
    int d = u >> 25;
    int c = (src >= 3 * csize) ? 3 : (src >= 2 * csize) ? 2 : (src >= csize) ? 1 : 0;
    atomicAdd(&cnt[d * 4 + c], 1);
  }
  __syncthreads();
  int tot = 0;
  if (t < 128) {
    int p0 = (cnt[t * 4 + 0] + 3) & ~3;
    int p1 = (cnt[t * 4 + 1] + 3) & ~3;
    int p2 = (cnt[t * 4 + 2] + 3) & ~3;
    int p3 = (cnt[t * 4 + 3] + 3) & ~3;
    loc[t * 4 + 0] = 0;
    loc[t * 4 + 1] = p0;
    loc[t * 4 + 2] = p0 + p1;
    loc[t * 4 + 3] = p0 + p1 + p2;
    tot = p0 + p1 + p2 + p3;
    sh[t] = tot;
  }
  __syncthreads();
  int x = tot;
  for (int d = 1; d < 128; d <<= 1) {
    int y = (t < 128 && t >= d) ? sh[t - d] : 0;
    __syncthreads();
    if (t < 128) {
      x += y;
      sh[t] = x;
    }
    __syncthreads();
  }
  if (t < 128) {
    int st = pb + x - tot;  // node's padded segment start (4-aligned)
    int node = (b << 7) + t;
    int s0 = st + loc[t * 4 + 0], s1 = st + loc[t * 4 + 1];
    int s2 = st + loc[t * 4 + 2], s3 = st + loc[t * 4 + 3];
    cur[t * 4 + 0] = s0;
    cur[t * 4 + 1] = s1;
    cur[t * 4 + 2] = s2;
    cur[t * 4 + 3] = s3;
    if (node < n) {
      off4[node] = make_int4(s0, s1, s2, s3);
      oend[node] = st + tot;
      int v = cnt[t * 4] + cnt[t * 4 + 1] + cnt[t * 4 + 2] + cnt[t * 4 + 3];
      dis[node] = rsqrtf((float)(v + 1));
    }
  }
  __syncthreads();
  for (int k = e0 + t; k < e1; k += 256) {
    unsigned u = buf[k];
    int src = (int)(u & 0x1FFFFFFu);
    int d = u >> 25;
    int c = (src >= 3 * csize) ? 3 : (src >= 2 * csize) ? 2 : (src >= csize) ? 1 : 0;
    int p = atomicAdd(&cur[d * 4 + c], 1);
    csr[p] = src;
  }
  __syncthreads();
  // fill pad slots with sentinel row n (cur now == sub-segment start + cnt)
  if (t < 128) {
#pragma unroll
    for (int c = 0; c < 4; ++c) {
      int k0 = t * 4 + c;
      int pad = ((cnt[k0] + 3) & ~3) - cnt[k0];
      int base = cur[k0];
      for (int q = 0; q < pad; ++q) csr[base + q] = n;
    }
  }
}

// layer 0: Hs(f16 row-major) = (X @ W) * dis[row] via MFMA
__global__ void __launch_bounds__(256) gemm_mfma_kernel(const float* __restrict__ Xf,
                                                        const _Float16* __restrict__ Wt,
                                                        const float* __restrict__ dis,
                                                        _Float16* __restrict__ Hs, int n) {
  __shared__ _Float16 st[64 * FEAT];  // 16 KB epilogue staging
  int tid = threadIdx.x;
  int w = tid >> 6, lane = tid & 63;
  int l15 = lane & 15, hi = lane >> 4;

  int rowA = blockIdx.x * 64 + w * 16 + l15;
  int rA = min(rowA, n - 1);

  f4 acc[8];
#pragma unroll
  for (int nb = 0; nb < 8; ++nb) acc[nb] = (f4)(0.f);

#pragma unroll
  for (int kk = 0; kk < FEAT; kk += 32) {
    int ko = kk + hi * 8;
    h8 a;
    float4 x0 = *(const float4*)&Xf[(size_t)rA * FEAT + ko];
    float4 x1 = *(const float4*)&Xf[(size_t)rA * FEAT + ko + 4];
    a[0] = (_Float16)x0.x; a[1] = (_Float16)x0.y; a[2] = (_Float16)x0.z; a[3] = (_Float16)x0.w;
    a[4] = (_Float16)x1.x; a[5] = (_Float16)x1.y; a[6] = (_Float16)x1.z; a[7] = (_Float16)x1.w;
#pragma unroll
    for (int nb = 0; nb < 8; ++nb) {
      h8 bfr = *(const h8*)&Wt[(nb * 16 + l15) * FEAT + ko];
      acc[nb] = __builtin_amdgcn_mfma_f32_16x16x32_f16(a, bfr, acc[nb], 0, 0, 0);
    }
  }

  float dv[4];
#pragma unroll
  for (int r = 0; r < 4; ++r) {
    int grow = blockIdx.x * 64 + w * 16 + hi * 4 + r;
    dv[r] = dis[min(grow, n - 1)];
  }
#pragma unroll
  for (int nb = 0; nb < 8; ++nb)
#pragma unroll
    for (int r = 0; r < 4; ++r)
      st[(w * 16 + hi * 4 + r) * FEAT + nb * 16 + l15] = (_Float16)(acc[nb][r] * dv[r]);
  __syncthreads();

  int rowbase = blockIdx.x * 64;
#pragma unroll
  for (int i = tid; i < 64 * FEAT / 8; i += 256) {
    int row = rowbase + (i >> 4);
    if (row < n)
      *(uint4*)&Hs[(size_t)row * FEAT + (i & 15) * 8] =
          *(const uint4*)&st[(i >> 4) * FEAT + (i & 15) * 8];
  }
}

// Fused: A = relu(dis*agg(Hs_in) + b_prev) per node (64 nodes -> swizzled LDS
// tile), then Hs_out = (A @ W) * dis via MFMA. 512 thr / 8 waves / 64 rows.
// Phase 1: chunk-outermost gather (4 chunks, block barrier per chunk);
// 32 groups x 2 nodes; 4-deep h8 loads; acc persists in registers.
__global__ void __launch_bounds__(512, 6) fused_kernel(const h8* __restrict__ Hs_in,
                                                       const int* __restrict__ csr,
                                                       const int4* __restrict__ off4,
                                                       const int* __restrict__ oend,
                                                       const float* __restrict__ dis,
                                                       const float* __restrict__ bias,
                                                       const _Float16* __restrict__ Wt,
                                                       _Float16* __restrict__ Hs_out, int n) {
  __shared__ char xsb[64 * 256];  // 16 KB: A-tile, then reused as epilogue staging
  int tid = threadIdx.x;
  int w = tid >> 6, lane = tid & 63;
  int grp = lane >> 4, lig = lane & 15;
  int row0 = blockIdx.x * 64;
  int g32 = w * 4 + grp;  // 0..31

  int nd0 = min(row0 + g32 * 2, n - 1);
  int nd1 = min(row0 + g32 * 2 + 1, n - 1);
  int4 o0 = off4[nd0], o1 = off4[nd1];
  int oe0 = oend[nd0], oe1 = oend[nd1];

  float acc0[8], acc1[8];
  h8 sv0 = Hs_in[(size_t)nd0 * 16 + lig];
  h8 sv1 = Hs_in[(size_t)nd1 * 16 + lig];
#pragma unroll
  for (int j = 0; j < 8; ++j) {
    acc0[j] = (float)sv0[j];
    acc1[j] = (float)sv1[j];
  }

  // ---- phase 1: chunk-outermost gather (hot slice = 3.2 MB, L2-resident) ----
#pragma unroll
  for (int c = 0; c < 4; ++c) {
    int s0 = (c == 0) ? o0.x : (c == 1) ? o0.y : (c == 2) ? o0.z : o0.w;
    int e0 = (c == 0) ? o0.y : (c == 1) ? o0.z : (c == 2) ? o0.w : oe0;
    for (int k = s0; k < e0; k += 4) {
      int4 ci = *(const int4*)&csr[k];
      h8 v0 = Hs_in[(size_t)ci.x * 16 + lig];
      h8 v1 = Hs_in[(size_t)ci.y * 16 + lig];
      h8 v2 = Hs_in[(size_t)ci.z * 16 + lig];
      h8 v3 = Hs_in[(size_t)ci.w * 16 + lig];
#pragma unroll
      for (int j = 0; j < 8; ++j)
        acc0[j] += ((float)v0[j] + (float)v1[j]) + ((float)v2[j] + (float)v3[j]);
    }
    int s1 = (c == 0) ? o1.x : (c == 1) ? o1.y : (c == 2) ? o1.z : o1.w;
    int e1 = (c == 0) ? o1.y : (c == 1) ? o1.z : (c == 2) ? o1.w : oe1;
    for (int k = s1; k < e1; k += 4) {
      int4 ci = *(const int4*)&csr[k];
      h8 v0 = Hs_in[(size_t)ci.x * 16 + lig];
      h8 v1 = Hs_in[(size_t)ci.y * 16 + lig];
      h8 v2 = Hs_in[(size_t)ci.z * 16 + lig];
      h8 v3 = Hs_in[(size_t)ci.w * 16 + lig];
#pragma unroll
      for (int j = 0; j < 8; ++j)
        acc1[j] += ((float)v0[j] + (float)v1[j]) + ((float)v2[j] + (float)v3[j]);
    }
    __syncthreads();  // keep block's waves chunk-aligned
  }

  // epilogue of phase 1: bias + dis + relu -> swizzled LDS A-tile
  float d0 = dis[nd0], d1 = dis[nd1];
  float4 bb0 = ((const float4*)bias)[lig * 2];
  float4 bb1 = ((const float4*)bias)[lig * 2 + 1];
  float bb[8] = {bb0.x, bb0.y, bb0.z, bb0.w, bb1.x, bb1.y, bb1.z, bb1.w};
  h8 oA, oB;
#pragma unroll
  for (int j = 0; j < 8; ++j) {
    oA[j] = (_Float16)fmaxf(fmaf(d0, acc0[j], bb[j]), 0.f);
    oB[j] = (_Float16)fmaxf(fmaf(d1, acc1[j], bb[j]), 0.f);
  }
  *(h8*)(xsb + swz(g32 * 2, lig * 16)) = oA;
  *(h8*)(xsb + swz(g32 * 2 + 1, lig * 16)) = oB;
  __syncthreads();

  // ---- phase 2: MFMA from LDS A-tile; wave = (strip = w&3, colhalf = w>>2) ----
  int l15 = lane & 15, hi = lane >> 4;
  int strip = w & 3, ch = w >> 2;
  f4 acc[4];
#pragma unroll
  for (int nb = 0; nb < 4; ++nb) acc[nb] = (f4)(0.f);
#pragma unroll
  for (int kk = 0; kk < FEAT; kk += 32) {
    int ko = kk + hi * 8;
    h8 a = *(const h8*)(xsb + swz(strip * 16 + l15, ko * 2));
#pragma unroll
    for (int nb = 0; nb < 4; ++nb) {
      h8 bfr = *(const h8*)&Wt[(ch * 64 + nb * 16 + l15) * FEAT + ko];
      acc[nb] = __builtin_amdgcn_mfma_f32_16x16x32_f16(a, bfr, acc[nb], 0, 0, 0);
    }
  }

  float dv[4];
#pragma unroll
  for (int r = 0; r < 4; ++r) {
    int grow = row0 + strip * 16 + hi * 4 + r;
    dv[r] = dis[min(grow, n - 1)];
  }
  __syncthreads();  // all A-reads done before reusing xsb as staging
#pragma unroll
  for (int nb = 0; nb < 4; ++nb)
#pragma unroll
    for (int r = 0; r < 4; ++r) {
      int srow = strip * 16 + hi * 4 + r;
      *(_Float16*)(xsb + swz(srow, (ch * 64 + nb * 16 + l15) * 2)) =
          (_Float16)(acc[nb][r] * dv[r]);
    }
  __syncthreads();
#pragma unroll
  for (int i = tid; i < 64 * FEAT / 8; i += 512) {
    int row = row0 + (i >> 4);
    if (row < n)
      *(uint4*)&Hs_out[(size_t)row * FEAT + (i & 15) * 8] =
          *(const uint4*)(xsb + swz(i >> 4, (i & 15) * 16));
  }
}

// Layer-2 agg standalone: single-range branchless scan over [off4.x, oend)
// (contiguous padded range, sentinel row n inside). No barriers, no chunks.
// 512 thr, 32 groups x 2 nodes, writes h8 rows for pool.
__global__ void __launch_bounds__(512, 6) agg_kernel(const h8* __restrict__ Hs,
                                                     const int* __restrict__ csr,
                                                     const int4* __restrict__ off4,
                                                     const int* __restrict__ oend,
                                                     const float* __restrict__ dis,
                                                     const float* __restrict__ bias,
                                                     h8* __restrict__ out, int n) {
  int tid = threadIdx.x;
  int g32 = tid >> 4, lig = tid & 15;  // 32 groups x 16 lanes
  int row0 = blockIdx.x * 64;

  float4 bb0 = ((const float4*)bias)[lig * 2];
  float4 bb1 = ((const float4*)bias)[lig * 2 + 1];
  float bb[8] = {bb0.x, bb0.y, bb0.z, bb0.w, bb1.x, bb1.y, bb1.z, bb1.w};

#pragma unroll
  for (int m = 0; m < 2; ++m) {
    int node = row0 + g32 * 2 + m;
    int nd = min(node, n - 1);
    int s = off4[nd].x;
    int e = oend[nd];
    float a0[8], a1[8];
    h8 sv = Hs[(size_t)nd * 16 + lig];  // self-loop term
#pragma unroll
    for (int j = 0; j < 8; ++j) {
      a0[j] = (float)sv[j];
      a1[j] = 0.f;
    }
    for (int k = s; k < e; k += 4) {
      int4 ci = *(const int4*)&csr[k];
      h8 v0 = Hs[(size_t)ci.x * 16 + lig];
      h8 v1 = Hs[(size_t)ci.y * 16 + lig];
      h8 v2 = Hs[(size_t)ci.z * 16 + lig];
      h8 v3 = Hs[(size_t)ci.w * 16 + lig];
#pragma unroll
      for (int j = 0; j < 8; ++j) a0[j] += (float)v0[j] + (float)v2[j];
#pragma unroll
      for (int j = 0; j < 8; ++j) a1[j] += (float)v1[j] + (float)v3[j];
    }
    float d = dis[nd];
    h8 o;
#pragma unroll
    for (int j = 0; j < 8; ++j)
      o[j] = (_Float16)fmaxf(fmaf(d, a0[j] + a1[j], bb[j]), 0.f);
    if (node < n) out[(size_t)node * 16 + lig] = o;
  }
}

// mean-pool per graph (f16 input) + linear(128->10) + log_softmax
__global__ void __launch_bounds__(128) pool_kernel(const __half* __restrict__ h,
                                                   const int* __restrict__ gstart,
                                                   const float* __restrict__ lw,
                                                   const float* __restrict__ lb,
                                                   float* __restrict__ out) {
  int g = blockIdx.x;
  int t = threadIdx.x;
  int s = gstart[g];
  int e = gstart[g + 1];
  float a0 = 0.f, a1 = 0.f, a2 = 0.f, a3 = 0.f;
  int i = s;
  for (; i + 4 <= e; i += 4) {
    a0 += __half2float(h[(size_t)i * FEAT + t]);
    a1 += __half2float(h[(size_t)(i + 1) * FEAT + t]);
    a2 += __half2float(h[(size_t)(i + 2) * FEAT + t]);
    a3 += __half2float(h[(size_t)(i + 3) * FEAT + t]);
  }
  for (; i < e; ++i) a0 += __half2float(h[(size_t)i * FEAT + t]);
  float acc = a0 + a1 + a2 + a3;
  float cnt = (float)(e - s);
  float pooled = acc / fmaxf(cnt, 1.f);
  __shared__ float lds[FEAT];
  __shared__ float logits[NCLASS];
  lds[t] = pooled;
  __syncthreads();
  if (t < NCLASS) {
    float z = lb[t];
    for (int k = 0; k < FEAT; ++k) z += lds[k] * lw[k * NCLASS + t];
    logits[t] = z;
  }
  __syncthreads();
  if (t < NCLASS) {
    float m = logits[0];
#pragma unroll
    for (int c = 1; c < NCLASS; ++c) m = fmaxf(m, logits[c]);
    float ssum = 0.f;
#pragma unroll
    for (int c = 0; c < NCLASS; ++c) ssum += expf(logits[c] - m);
    out[(size_t)g * NCLASS + t] = logits[t] - m - logf(ssum);
  }
}

extern "C" void kernel_launch(void* const* d_in, const int* in_sizes, int n_in,
                              void* d_out, int out_size, void* d_ws, size_t ws_size,
                              hipStream_t stream) {
  const float* x = (const float*)d_in[0];
  const int* ei = (const int*)d_in[1];
  const int* batch = (const int*)d_in[2];
  const float* W0 = (const float*)d_in[3];
  const float* b0 = (const float*)d_in[4];
  const float* W1 = (const float*)d_in[5];
  const float* b1 = (const float*)d_in[6];
  const float* W2 = (const float*)d_in[7];
  const float* b2 = (const float*)d_in[8];
  const float* lw = (const float*)d_in[9];
  const float* lb = (const float*)d_in[10];

  int n = in_sizes[2];        // 50000 nodes
  int ne = in_sizes[1] / 2;   // 800000 edges
  int g = out_size / NCLASS;  // 512 graphs
  int nb = (n + 127) >> 7;    // dst buckets (391)
  int csize = (n + 3) / 4;    // src chunk size (12500)
  int hblocks = 120;
  int epb = (ne + hblocks - 1) / hblocks;
  int wtblocks = (3 * FEAT * FEAT + 255) / 256;  // 192
  int bndblocks = (n + 255) / 256;

  char* ws = (char*)d_ws;
  size_t p = 0;
  auto alloc = [&](size_t bytes) {
    size_t cur = p;
    p += (bytes + 255) & ~(size_t)255;
    return cur;
  };
  int4* off4 = (int4*)(ws + alloc((size_t)n * 16));
  int* oend = (int*)(ws + alloc((size_t)n * 4));
  int* csr = (int*)(ws + alloc(((size_t)ne + 2048 * (size_t)nb + 64) * 4));
  int* bhist = (int*)(ws + alloc((size_t)NB_MAX * 4));
  int* bstart = (int*)(ws + alloc((size_t)(NB_MAX + 1) * 4));
  int* bcur = (int*)(ws + alloc((size_t)NB_MAX * 4));
  int* gstart = (int*)(ws + alloc((size_t)(g + 1) * 4));
  float* dis = (float*)(ws + alloc((size_t)n * 4));
  unsigned* buf = (unsigned*)(ws + alloc((size_t)ne * 4));
  _Float16* Wt = (_Float16*)(ws + alloc((size_t)3 * FEAT * FEAT * 2));
  _Float16* HA = (_Float16*)(ws + alloc((size_t)(n + 1) * FEAT * 2));  // +1 zero row
  _Float16* HB = (_Float16*)(ws + alloc((size_t)(n + 1) * FEAT * 2));

  hipMemsetAsync(bhist, 0, NB_MAX * 4, stream);
  hipMemsetAsync(HA + (size_t)n * FEAT, 0, FEAT * 2, stream);  // sentinel zero rows
  hipMemsetAsync(HB + (size_t)n * FEAT, 0, FEAT * 2, stream);

  prep_kernel<<<hblocks + wtblocks + bndblocks, 256, 0, stream>>>(
      ei, bhist, ne, nb, epb, hblocks, W0, W1, W2, Wt, wtblocks, batch, gstart, n, g);
  bscan_kernel<<<1, 512, 0, stream>>>(bhist, bstart, bcur, nb, ne);
  scatter_kernel<<<hblocks, 256, 0, stream>>>(ei, bcur, buf, ne, nb, epb);
  bucket_build_kernel<<<nb, 256, 0, stream>>>(buf, bstart, off4, oend, csr, dis, n, csize);

  int gblocks = (n + 63) / 64;
  // layer 0: X(f32) @ W0 * dis -> HA
  gemm_mfma_kernel<<<gblocks, 256, 0, stream>>>(x, Wt, dis, HA, n);
  // layer 0 agg + layer 1 gemm: HA -> HB
  fused_kernel<<<gblocks, 512, 0, stream>>>((const h8*)HA, csr, off4, oend, dis, b0,
                                            Wt + (size_t)1 * FEAT * FEAT, HB, n);
  // layer 1 agg + layer 2 gemm: HB -> HA
  fused_kernel<<<gblocks, 512, 0, stream>>>((const h8*)HB, csr, off4, oend, dis, b1,
                                            Wt + (size_t)2 * FEAT * FEAT, HA, n);
  // layer 2 agg: HA -> HB (pool input)
  agg_kernel<<<gblocks, 512, 0, stream>>>((const h8*)HA, csr, off4, oend, dis, b2,
                                          (h8*)HB, n);

  pool_kernel<<<g, 128, 0, stream>>>((const __half*)HB, gstart, lw, lb, (float*)d_out);
}

// Round 15
// 201.558 us; speedup vs baseline: 1.1816x; 1.0677x over previous
//
#include <hip/hip_runtime.h>
#include <hip/hip_fp16.h>

// GCN forward: 3x (MFMA GEMM + normalized adjacency aggregate + ReLU) + mean-pool + linear + log_softmax
// N=50000, E=800000, F=H=128, C=10, G=512
// Round 15: fixed-capacity buckets (mean 2046, sigma 45 -> 3072 slots) delete the
// histogram pass, bscan kernel, and all memsets: ei read ONCE, 8 kernels total.
// Gather kernels unchanged from r14 (structural ~47us/pass floor).

#define FEAT 128
#define NCLASS 10
#define NB_MAX 512   // max dst buckets (n <= 65536 here: 391)
#define BCAP 3072    // buf slots per bucket (mean 2046 + 22 sigma)
#define CSTRIDE 4608 // csr slots per bucket (BCAP + worst-case pad4)

typedef _Float16 h8 __attribute__((ext_vector_type(8)));
typedef float f4 __attribute__((ext_vector_type(4)));

// LDS tile swizzle: row stride 256B; XOR row&7 into byte bits 4..6.
__device__ inline int swz(int row, int cbyte) { return row * 256 + (cbyte ^ ((row & 7) << 4)); }

// ---- pass 0 combined: utility (block 0: zero bcur + H sentinels) + Wt convert
// (blocks [1,1+wtb)) + graph bounds (rest) ----
__global__ void __launch_bounds__(256) prep_kernel(const float* __restrict__ W0,
                                                   const float* __restrict__ W1,
                                                   const float* __restrict__ W2,
                                                   _Float16* __restrict__ Wt, int wtb,
                                                   const int* __restrict__ batch,
                                                   int* __restrict__ gstart, int n, int g,
                                                   int* __restrict__ bcur,
                                                   unsigned* __restrict__ HA32,
                                                   unsigned* __restrict__ HB32) {
  int t = threadIdx.x;
  if (blockIdx.x == 0) {
    for (int i = t; i < NB_MAX; i += 256) bcur[i] = 0;
    // zero sentinel row n of HA/HB (64 uints each)
    if (t < 64) HA32[(size_t)n * 64 + t] = 0u;
    else if (t < 128) HB32[(size_t)n * 64 + (t - 64)] = 0u;
    return;
  }
  if (blockIdx.x <= wtb) {
    // Wt[l][n][k] = W_l[k][n]
    int i = (blockIdx.x - 1) * 256 + t;
    if (i < 3 * FEAT * FEAT) {
      int l = i / (FEAT * FEAT);
      int r = i - l * (FEAT * FEAT);
      int nn = r >> 7, kk = r & 127;
      const float* W = (l == 0) ? W0 : (l == 1) ? W1 : W2;
      Wt[i] = (_Float16)W[kk * FEAT + nn];
    }
    return;
  }
  // graph boundaries from sorted batch
  int i = (blockIdx.x - 1 - wtb) * 256 + t;
  if (i >= n) return;
  int bi = batch[i];
  int bp = (i == 0) ? -1 : batch[i - 1];
  for (int q = bp + 1; q <= bi; ++q) gstart[q] = i;
  if (i == n - 1)
    for (int q = bi + 1; q <= g; ++q) gstart[q] = n;
}

// ---- pass 1: scatter packed (dst&127,src) into fixed-capacity dst-buckets ----
// reads ei ONCE; bcur[b] ends as the bucket's edge count.
__global__ void __launch_bounds__(256) scatter_kernel(const int* __restrict__ ei,
                                                      int* __restrict__ bcur,
                                                      unsigned* __restrict__ buf,
                                                      int ne, int nb, int epb) {
  __shared__ int lh[NB_MAX], lbs[NB_MAX];
  int t = threadIdx.x;
  for (int i = t; i < nb; i += 256) lh[i] = 0;
  __syncthreads();
  int r0 = blockIdx.x * epb;
  int r1 = min(r0 + epb, ne);
  for (int k = r0 + t; k < r1; k += 256) atomicAdd(&lh[ei[ne + k] >> 7], 1);
  __syncthreads();
  for (int i = t; i < nb; i += 256) {
    int c = lh[i];
    lbs[i] = c ? atomicAdd(&bcur[i], c) : 0;
    lh[i] = 0;  // reuse as local cursor
  }
  __syncthreads();
  for (int k = r0 + t; k < r1; k += 256) {
    int src = ei[k];
    int dst = ei[ne + k];
    int b = dst >> 7;
    int p = lbs[b] + atomicAdd(&lh[b], 1);
    buf[(size_t)b * BCAP + p] = (unsigned)src | ((unsigned)(dst & 127) << 25);
  }
}

// ---- pass 2: one block per bucket: per-(node,chunk) count -> pad4 scan ->
// off4/oend/dis/csr. Chunk = src/csize (4 chunks). Sub-segments pad4'd with n.
__global__ void __launch_bounds__(256) bucket_build_kernel(const unsigned* __restrict__ buf,
                                                           const int* __restrict__ bcnt,
                                                           int4* __restrict__ off4,
                                                           int* __restrict__ oend,
                                                           int* __restrict__ csr,
                                                           float* __restrict__ dis,
                                                           int n, int csize) {
  __shared__ int cnt[512], cur[512], loc[512], sh[128];
  int b = blockIdx.x, t = threadIdx.x;
  int e0 = b * BCAP;
  int e1 = e0 + bcnt[b];
  int pb = b * CSTRIDE;  // padded 4-aligned bucket base in csr
  for (int i = t; i < 512; i += 256) cnt[i] = 0;
  __syncthreads();
  for (int k = e0 + t; k < e1; k += 256) {
    unsigned u = buf[k];
    int src = (int)(u & 0x1FFFFFFu);
    int d = u >> 25;
    int c = (src >= 3 * csize) ? 3 : (src >= 2 * csize) ? 2 : (src >= csize) ? 1 : 0;
    atomicAdd(&cnt[d * 4 + c], 1);
  }
  __syncthreads();
  int tot = 0;
  if (t < 128) {
    int p0 = (cnt[t * 4 + 0] + 3) & ~3;
    int p1 = (cnt[t * 4 + 1] + 3) & ~3;
    int p2 = (cnt[t * 4 + 2] + 3) & ~3;
    int p3 = (cnt[t * 4 + 3] + 3) & ~3;
    loc[t * 4 + 0] = 0;
    loc[t * 4 + 1] = p0;
    loc[t * 4 + 2] = p0 + p1;
    loc[t * 4 + 3] = p0 + p1 + p2;
    tot = p0 + p1 + p2 + p3;
    sh[t] = tot;
  }
  __syncthreads();
  int x = tot;
  for (int d = 1; d < 128; d <<= 1) {
    int y = (t < 128 && t >= d) ? sh[t - d] : 0;
    __syncthreads();
    if (t < 128) {
      x += y;
      sh[t] = x;
    }
    __syncthreads();
  }
  if (t < 128) {
    int st = pb + x - tot;  // node's padded segment start (4-aligned)
    int node = (b << 7) + t;
    int s0 = st + loc[t * 4 + 0], s1 = st + loc[t * 4 + 1];
    int s2 = st + loc[t * 4 + 2], s3 = st + loc[t * 4 + 3];
    cur[t * 4 + 0] = s0;
    cur[t * 4 + 1] = s1;
    cur[t * 4 + 2] = s2;
    cur[t * 4 + 3] = s3;
    if (node < n) {
      off4[node] = make_int4(s0, s1, s2, s3);
      oend[node] = st + tot;
      int v = cnt[t * 4] + cnt[t * 4 + 1] + cnt[t * 4 + 2] + cnt[t * 4 + 3];
      dis[node] = rsqrtf((float)(v + 1));
    }
  }
  __syncthreads();
  for (int k = e0 + t; k < e1; k += 256) {
    unsigned u = buf[k];
    int src = (int)(u & 0x1FFFFFFu);
    int d = u >> 25;
    int c = (src >= 3 * csize) ? 3 : (src >= 2 * csize) ? 2 : (src >= csize) ? 1 : 0;
    int p = atomicAdd(&cur[d * 4 + c], 1);
    csr[p] = src;
  }
  __syncthreads();
  // fill pad slots with sentinel row n (cur now == sub-segment start + cnt)
  if (t < 128) {
#pragma unroll
    for (int c = 0; c < 4; ++c) {
      int k0 = t * 4 + c;
      int pad = ((cnt[k0] + 3) & ~3) - cnt[k0];
      int base = cur[k0];
      for (int q = 0; q < pad; ++q) csr[base + q] = n;
    }
  }
}

// layer 0: Hs(f16 row-major) = (X @ W) * dis[row] via MFMA
__global__ void __launch_bounds__(256) gemm_mfma_kernel(const float* __restrict__ Xf,
                                                        const _Float16* __restrict__ Wt,
                                                        const float* __restrict__ dis,
                                                        _Float16* __restrict__ Hs, int n) {
  __shared__ _Float16 st[64 * FEAT];  // 16 KB epilogue staging
  int tid = threadIdx.x;
  int w = tid >> 6, lane = tid & 63;
  int l15 = lane & 15, hi = lane >> 4;

  int rowA = blockIdx.x * 64 + w * 16 + l15;
  int rA = min(rowA, n - 1);

  f4 acc[8];
#pragma unroll
  for (int nb = 0; nb < 8; ++nb) acc[nb] = (f4)(0.f);

#pragma unroll
  for (int kk = 0; kk < FEAT; kk += 32) {
    int ko = kk + hi * 8;
    h8 a;
    float4 x0 = *(const float4*)&Xf[(size_t)rA * FEAT + ko];
    float4 x1 = *(const float4*)&Xf[(size_t)rA * FEAT + ko + 4];
    a[0] = (_Float16)x0.x; a[1] = (_Float16)x0.y; a[2] = (_Float16)x0.z; a[3] = (_Float16)x0.w;
    a[4] = (_Float16)x1.x; a[5] = (_Float16)x1.y; a[6] = (_Float16)x1.z; a[7] = (_Float16)x1.w;
#pragma unroll
    for (int nb = 0; nb < 8; ++nb) {
      h8 bfr = *(const h8*)&Wt[(nb * 16 + l15) * FEAT + ko];
      acc[nb] = __builtin_amdgcn_mfma_f32_16x16x32_f16(a, bfr, acc[nb], 0, 0, 0);
    }
  }

  float dv[4];
#pragma unroll
  for (int r = 0; r < 4; ++r) {
    int grow = blockIdx.x * 64 + w * 16 + hi * 4 + r;
    dv[r] = dis[min(grow, n - 1)];
  }
#pragma unroll
  for (int nb = 0; nb < 8; ++nb)
#pragma unroll
    for (int r = 0; r < 4; ++r)
      st[(w * 16 + hi * 4 + r) * FEAT + nb * 16 + l15] = (_Float16)(acc[nb][r] * dv[r]);
  __syncthreads();

  int rowbase = blockIdx.x * 64;
#pragma unroll
  for (int i = tid; i < 64 * FEAT / 8; i += 256) {
    int row = rowbase + (i >> 4);
    if (row < n)
      *(uint4*)&Hs[(size_t)row * FEAT + (i & 15) * 8] =
          *(const uint4*)&st[(i >> 4) * FEAT + (i & 15) * 8];
  }
}

// Fused: A = relu(dis*agg(Hs_in) + b_prev) per node (64 nodes -> swizzled LDS
// tile), then Hs_out = (A @ W) * dis via MFMA. 512 thr / 8 waves / 64 rows.
// Phase 1: chunk-outermost gather (4 chunks, block barrier per chunk);
// 32 groups x 2 nodes; 4-deep h8 loads; acc persists in registers.
__global__ void __launch_bounds__(512, 6) fused_kernel(const h8* __restrict__ Hs_in,
                                                       const int* __restrict__ csr,
                                                       const int4* __restrict__ off4,
                                                       const int* __restrict__ oend,
                                                       const float* __restrict__ dis,
                                                       const float* __restrict__ bias,
                                                       const _Float16* __restrict__ Wt,
                                                       _Float16* __restrict__ Hs_out, int n) {
  __shared__ char xsb[64 * 256];  // 16 KB: A-tile, then reused as epilogue staging
  int tid = threadIdx.x;
  int w = tid >> 6, lane = tid & 63;
  int grp = lane >> 4, lig = lane & 15;
  int row0 = blockIdx.x * 64;
  int g32 = w * 4 + grp;  // 0..31

  int nd0 = min(row0 + g32 * 2, n - 1);
  int nd1 = min(row0 + g32 * 2 + 1, n - 1);
  int4 o0 = off4[nd0], o1 = off4[nd1];
  int oe0 = oend[nd0], oe1 = oend[nd1];

  float acc0[8], acc1[8];
  h8 sv0 = Hs_in[(size_t)nd0 * 16 + lig];
  h8 sv1 = Hs_in[(size_t)nd1 * 16 + lig];
#pragma unroll
  for (int j = 0; j < 8; ++j) {
    acc0[j] = (float)sv0[j];
    acc1[j] = (float)sv1[j];
  }

  // ---- phase 1: chunk-outermost gather (hot slice = 3.2 MB, L2-resident) ----
#pragma unroll
  for (int c = 0; c < 4; ++c) {
    int s0 = (c == 0) ? o0.x : (c == 1) ? o0.y : (c == 2) ? o0.z : o0.w;
    int e0 = (c == 0) ? o0.y : (c == 1) ? o0.z : (c == 2) ? o0.w : oe0;
    for (int k = s0; k < e0; k += 4) {
      int4 ci = *(const int4*)&csr[k];
      h8 v0 = Hs_in[(size_t)ci.x * 16 + lig];
      h8 v1 = Hs_in[(size_t)ci.y * 16 + lig];
      h8 v2 = Hs_in[(size_t)ci.z * 16 + lig];
      h8 v3 = Hs_in[(size_t)ci.w * 16 + lig];
#pragma unroll
      for (int j = 0; j < 8; ++j)
        acc0[j] += ((float)v0[j] + (float)v1[j]) + ((float)v2[j] + (float)v3[j]);
    }
    int s1 = (c == 0) ? o1.x : (c == 1) ? o1.y : (c == 2) ? o1.z : o1.w;
    int e1 = (c == 0) ? o1.y : (c == 1) ? o1.z : (c == 2) ? o1.w : oe1;
    for (int k = s1; k < e1; k += 4) {
      int4 ci = *(const int4*)&csr[k];
      h8 v0 = Hs_in[(size_t)ci.x * 16 + lig];
      h8 v1 = Hs_in[(size_t)ci.y * 16 + lig];
      h8 v2 = Hs_in[(size_t)ci.z * 16 + lig];
      h8 v3 = Hs_in[(size_t)ci.w * 16 + lig];
#pragma unroll
      for (int j = 0; j < 8; ++j)
        acc1[j] += ((float)v0[j] + (float)v1[j]) + ((float)v2[j] + (float)v3[j]);
    }
    __syncthreads();  // keep block's waves chunk-aligned
  }

  // epilogue of phase 1: bias + dis + relu -> swizzled LDS A-tile
  float d0 = dis[nd0], d1 = dis[nd1];
  float4 bb0 = ((const float4*)bias)[lig * 2];
  float4 bb1 = ((const float4*)bias)[lig * 2 + 1];
  float bb[8] = {bb0.x, bb0.y, bb0.z, bb0.w, bb1.x, bb1.y, bb1.z, bb1.w};
  h8 oA, oB;
#pragma unroll
  for (int j = 0; j < 8; ++j) {
    oA[j] = (_Float16)fmaxf(fmaf(d0, acc0[j], bb[j]), 0.f);
    oB[j] = (_Float16)fmaxf(fmaf(d1, acc1[j], bb[j]), 0.f);
  }
  *(h8*)(xsb + swz(g32 * 2, lig * 16)) = oA;
  *(h8*)(xsb + swz(g32 * 2 + 1, lig * 16)) = oB;
  __syncthreads();

  // ---- phase 2: MFMA from LDS A-tile; wave = (strip = w&3, colhalf = w>>2) ----
  int l15 = lane & 15, hi = lane >> 4;
  int strip = w & 3, ch = w >> 2;
  f4 acc[4];
#pragma unroll
  for (int nb = 0; nb < 4; ++nb) acc[nb] = (f4)(0.f);
#pragma unroll
  for (int kk = 0; kk < FEAT; kk += 32) {
    int ko = kk + hi * 8;
    h8 a = *(const h8*)(xsb + swz(strip * 16 + l15, ko * 2));
#pragma unroll
    for (int nb = 0; nb < 4; ++nb) {
      h8 bfr = *(const h8*)&Wt[(ch * 64 + nb * 16 + l15) * FEAT + ko];
      acc[nb] = __builtin_amdgcn_mfma_f32_16x16x32_f16(a, bfr, acc[nb], 0, 0, 0);
    }
  }

  float dv[4];
#pragma unroll
  for (int r = 0; r < 4; ++r) {
    int grow = row0 + strip * 16 + hi * 4 + r;
    dv[r] = dis[min(grow, n - 1)];
  }
  __syncthreads();  // all A-reads done before reusing xsb as staging
#pragma unroll
  for (int nb = 0; nb < 4; ++nb)
#pragma unroll
    for (int r = 0; r < 4; ++r) {
      int srow = strip * 16 + hi * 4 + r;
      *(_Float16*)(xsb + swz(srow, (ch * 64 + nb * 16 + l15) * 2)) =
          (_Float16)(acc[nb][r] * dv[r]);
    }
  __syncthreads();
#pragma unroll
  for (int i = tid; i < 64 * FEAT / 8; i += 512) {
    int row = row0 + (i >> 4);
    if (row < n)
      *(uint4*)&Hs_out[(size_t)row * FEAT + (i & 15) * 8] =
          *(const uint4*)(xsb + swz(i >> 4, (i & 15) * 16));
  }
}

// Layer-2 agg standalone: single-range branchless scan over [off4.x, oend)
// (contiguous padded range, sentinel row n inside). No barriers, no chunks.
// 512 thr, 32 groups x 2 nodes, writes h8 rows for pool.
__global__ void __launch_bounds__(512, 6) agg_kernel(const h8* __restrict__ Hs,
                                                     const int* __restrict__ csr,
                                                     const int4* __restrict__ off4,
                                                     const int* __restrict__ oend,
                                                     const float* __restrict__ dis,
                                                     const float* __restrict__ bias,
                                                     h8* __restrict__ out, int n) {
  int tid = threadIdx.x;
  int g32 = tid >> 4, lig = tid & 15;  // 32 groups x 16 lanes
  int row0 = blockIdx.x * 64;

  float4 bb0 = ((const float4*)bias)[lig * 2];
  float4 bb1 = ((const float4*)bias)[lig * 2 + 1];
  float bb[8] = {bb0.x, bb0.y, bb0.z, bb0.w, bb1.x, bb1.y, bb1.z, bb1.w};

#pragma unroll
  for (int m = 0; m < 2; ++m) {
    int node = row0 + g32 * 2 + m;
    int nd = min(node, n - 1);
    int s = off4[nd].x;
    int e = oend[nd];
    float a0[8], a1[8];
    h8 sv = Hs[(size_t)nd * 16 + lig];  // self-loop term
#pragma unroll
    for (int j = 0; j < 8; ++j) {
      a0[j] = (float)sv[j];
      a1[j] = 0.f;
    }
    for (int k = s; k < e; k += 4) {
      int4 ci = *(const int4*)&csr[k];
      h8 v0 = Hs[(size_t)ci.x * 16 + lig];
      h8 v1 = Hs[(size_t)ci.y * 16 + lig];
      h8 v2 = Hs[(size_t)ci.z * 16 + lig];
      h8 v3 = Hs[(size_t)ci.w * 16 + lig];
#pragma unroll
      for (int j = 0; j < 8; ++j) a0[j] += (float)v0[j] + (float)v2[j];
#pragma unroll
      for (int j = 0; j < 8; ++j) a1[j] += (float)v1[j] + (float)v3[j];
    }
    float d = dis[nd];
    h8 o;
#pragma unroll
    for (int j = 0; j < 8; ++j)
      o[j] = (_Float16)fmaxf(fmaf(d, a0[j] + a1[j], bb[j]), 0.f);
    if (node < n) out[(size_t)node * 16 + lig] = o;
  }
}

// mean-pool per graph (f16 input) + linear(128->10) + log_softmax
__global__ void __launch_bounds__(128) pool_kernel(const __half* __restrict__ h,
                                                   const int* __restrict__ gstart,
                                                   const float* __restrict__ lw,
                                                   const float* __restrict__ lb,
                                                   float* __restrict__ out) {
  int g = blockIdx.x;
  int t = threadIdx.x;
  int s = gstart[g];
  int e = gstart[g + 1];
  float a0 = 0.f, a1 = 0.f, a2 = 0.f, a3 = 0.f;
  int i = s;
  for (; i + 4 <= e; i += 4) {
    a0 += __half2float(h[(size_t)i * FEAT + t]);
    a1 += __half2float(h[(size_t)(i + 1) * FEAT + t]);
    a2 += __half2float(h[(size_t)(i + 2) * FEAT + t]);
    a3 += __half2float(h[(size_t)(i + 3) * FEAT + t]);
  }
  for (; i < e; ++i) a0 += __half2float(h[(size_t)i * FEAT + t]);
  float acc = a0 + a1 + a2 + a3;
  float cnt = (float)(e - s);
  float pooled = acc / fmaxf(cnt, 1.f);
  __shared__ float lds[FEAT];
  __shared__ float logits[NCLASS];
  lds[t] = pooled;
  __syncthreads();
  if (t < NCLASS) {
    float z = lb[t];
    for (int k = 0; k < FEAT; ++k) z += lds[k] * lw[k * NCLASS + t];
    logits[t] = z;
  }
  __syncthreads();
  if (t < NCLASS) {
    float m = logits[0];
#pragma unroll
    for (int c = 1; c < NCLASS; ++c) m = fmaxf(m, logits[c]);
    float ssum = 0.f;
#pragma unroll
    for (int c = 0; c < NCLASS; ++c) ssum += expf(logits[c] - m);
    out[(size_t)g * NCLASS + t] = logits[t] - m - logf(ssum);
  }
}

extern "C" void kernel_launch(void* const* d_in, const int* in_sizes, int n_in,
                              void* d_out, int out_size, void* d_ws, size_t ws_size,
                              hipStream_t stream) {
  const float* x = (const float*)d_in[0];
  const int* ei = (const int*)d_in[1];
  const int* batch = (const int*)d_in[2];
  const float* W0 = (const float*)d_in[3];
  const float* b0 = (const float*)d_in[4];
  const float* W1 = (const float*)d_in[5];
  const float* b1 = (const float*)d_in[6];
  const float* W2 = (const float*)d_in[7];
  const float* b2 = (const float*)d_in[8];
  const float* lw = (const float*)d_in[9];
  const float* lb = (const float*)d_in[10];

  int n = in_sizes[2];        // 50000 nodes
  int ne = in_sizes[1] / 2;   // 800000 edges
  int g = out_size / NCLASS;  // 512 graphs
  int nb = (n + 127) >> 7;    // dst buckets (391)
  int csize = (n + 3) / 4;    // src chunk size (12500)
  int hblocks = 120;
  int epb = (ne + hblocks - 1) / hblocks;
  int wtblocks = (3 * FEAT * FEAT + 255) / 256;  // 192
  int bndblocks = (n + 255) / 256;

  char* ws = (char*)d_ws;
  size_t p = 0;
  auto alloc = [&](size_t bytes) {
    size_t cur = p;
    p += (bytes + 255) & ~(size_t)255;
    return cur;
  };
  int4* off4 = (int4*)(ws + alloc((size_t)n * 16));
  int* oend = (int*)(ws + alloc((size_t)n * 4));
  int* csr = (int*)(ws + alloc((size_t)nb * CSTRIDE * 4));
  int* bcur = (int*)(ws + alloc((size_t)NB_MAX * 4));
  int* gstart = (int*)(ws + alloc((size_t)(g + 1) * 4));
  float* dis = (float*)(ws + alloc((size_t)n * 4));
  unsigned* buf = (unsigned*)(ws + alloc((size_t)nb * BCAP * 4));
  _Float16* Wt = (_Float16*)(ws + alloc((size_t)3 * FEAT * FEAT * 2));
  _Float16* HA = (_Float16*)(ws + alloc((size_t)(n + 1) * FEAT * 2));  // +1 zero row
  _Float16* HB = (_Float16*)(ws + alloc((size_t)(n + 1) * FEAT * 2));

  prep_kernel<<<1 + wtblocks + bndblocks, 256, 0, stream>>>(
      W0, W1, W2, Wt, wtblocks, batch, gstart, n, g, bcur, (unsigned*)HA, (unsigned*)HB);
  scatter_kernel<<<hblocks, 256, 0, stream>>>(ei, bcur, buf, ne, nb, epb);
  bucket_build_kernel<<<nb, 256, 0, stream>>>(buf, bcur, off4, oend, csr, dis, n, csize);

  int gblocks = (n + 63) / 64;
  // layer 0: X(f32) @ W0 * dis -> HA
  gemm_mfma_kernel<<<gblocks, 256, 0, stream>>>(x, Wt, dis, HA, n);
  // layer 0 agg + layer 1 gemm: HA -> HB
  fused_kernel<<<gblocks, 512, 0, stream>>>((const h8*)HA, csr, off4, oend, dis, b0,
                                            Wt + (size_t)1 * FEAT * FEAT, HB, n);
  // layer 1 agg + layer 2 gemm: HB -> HA
  fused_kernel<<<gblocks, 512, 0, stream>>>((const h8*)HB, csr, off4, oend, dis, b1,
                                            Wt + (size_t)2 * FEAT * FEAT, HA, n);
  // layer 2 agg: HA -> HB (pool input)
  agg_kernel<<<gblocks, 512, 0, stream>>>((const h8*)HA, csr, off4, oend, dis, b2,
                                          (h8*)HB, n);

  pool_kernel<<<g, 128, 0, stream>>>((const __half*)HB, gstart, lw, lb, (float*)d_out);
}